// Round 6
// baseline (295.358 us; speedup 1.0000x reference)
//
#include <hip/hip_runtime.h>
#include <math.h>
#include <stdint.h>

#define NB   4
#define NC   1025
#define WSZ  2048
#define STEP 1024
#define FRM  256
#define BAT  32
#define TT   262144
#define SEGS 4       // segments (frames) per workgroup in fused synth
#define KC   16      // bin chunk per rc-build in the synth kernel
#define YPAD 68      // floats per 64-sample ystage chunk (+4 pad: conflict-free strides)

// 1/2048 (exact): phases are integers mod 2048 -> revolutions for v_sin/v_cos
#define RREV (1.0f / 2048.0f)

typedef float f2 __attribute__((ext_vector_type(2)));

__device__ __forceinline__ float tanh_fast(float z) {
    float e = __expf(2.0f * z);
    return 1.0f - 2.0f / (e + 1.0f);   // exact tanh identity; inf/0 saturate to +/-1
}

// hardware cis: idx taken mod 2048, argument in revolutions (exact, no range reduction)
__device__ __forceinline__ void cis_rev(int idx, float* c, float* s) {
    float rev = (float)(idx & 2047) * RREV;
    *c = __builtin_amdgcn_cosf(rev);
    *s = __builtin_amdgcn_sinf(rev);
}

// broadcast lane l's value (uniform l) to all lanes via v_readlane
__device__ __forceinline__ float rl(float v, int l) {
    return __int_as_float(__builtin_amdgcn_readlane(__float_as_int(v), l));
}

// ---------------- setup + tables fused: compact bins, softmax(mixer), hann, cisA/cisB ----------------
__global__ __launch_bounds__(1024) void setup_kernel(
    const float* __restrict__ transfers, const float* __restrict__ mixer,
    int* __restrict__ counts, int* __restrict__ bins, float* __restrict__ tvals,
    float* __restrict__ wmix, float* __restrict__ hann,
    float2* __restrict__ cisA, float2* __restrict__ cisB, int kmax)
{
    int i = blockIdx.x, tid = threadIdx.x;
    __shared__ int wcnt[16], woff[16];
    __shared__ int sK;
    if (i == 0) {                                   // hann[n] = 0.5 - 0.5 cos(2pi n/2048)
        float cc, ss; cis_rev(tid, &cc, &ss);
        hann[tid] = 0.5f - 0.5f * cc;
    }
    float tv = transfers[i * NC + tid];
    bool nz = (tv != 0.0f);
    unsigned long long mask = __ballot(nz);
    int lane = tid & 63, w = tid >> 6;
    int within = __popcll(mask & ((1ULL << lane) - 1ULL));
    if (lane == 0) wcnt[w] = __popcll(mask);
    __syncthreads();
    if (tid == 0) {
        int acc = 0;
        for (int q = 0; q < 16; ++q) { woff[q] = acc; acc += wcnt[q]; }
        float tvL = transfers[i * NC + 1024];       // tail bin k=1024
        if (tvL != 0.0f && acc < kmax) { bins[i * NC + acc] = 1024; tvals[i * NC + acc] = tvL; acc++; }
        int kk = (acc < kmax) ? acc : kmax;
        counts[i] = kk;
        sK = kk;
        if (i == 0) {                               // softmax of mixer[5]
            float m = mixer[0];
            for (int q = 1; q < 5; ++q) m = fmaxf(m, mixer[q]);
            float e[5], s = 0.f;
            for (int q = 0; q < 5; ++q) { e[q] = __expf(mixer[q] - m); s += e[q]; }
            for (int q = 0; q < 5; ++q) wmix[q] = e[q] / s;
        }
    }
    __syncthreads();
    if (nz) {
        int pos = woff[w] + within;
        if (pos < kmax) { bins[i * NC + pos] = tid; tvals[i * NC + pos] = tv; }
    }
    __syncthreads();                                // bins visible to table phase
    int K = sK;
    // table phase: cisA[i][j][m] = cis(2pi k_j m/2048) m<64; cisB[i][j][q] = cis(2pi k_j 64q/2048) q<16
    for (int flat = tid; flat < K * 80; flat += 1024) {
        int j = flat / 80, r = flat - j * 80;
        int k = bins[i * NC + j];
        if (r < 64) {
            float cc, ss; cis_rev(k * r, &cc, &ss);
            cisA[((size_t)i * kmax + j) * 64 + r] = make_float2(cc, ss);
        } else {
            int q = r - 64;
            float cc, ss; cis_rev(k * 64 * q, &cc, &ss);
            cisB[((size_t)i * kmax + j) * 16 + q] = make_float2(cc, ss);
        }
    }
}

// shared half-frame DFT (standalone analysis of x only): xr[16] per lane (n = lane + 64*i),
// bins j = w, w+4, ... < K; W = conj(cisB[j][1]); final rotate by conj(cisA[j][lane]).
__device__ __forceinline__ void half_dft(
    const float xr[16], int K, const float2* __restrict__ cA,
    const float2* __restrict__ cB, float2* __restrict__ Hout, int lane, int w)
{
    for (int j = w; j < K; j += 8) {
        int j2 = j + 4;
        bool two = (j2 < K);
        float2 bA = cB[(size_t)j * 16 + 1];
        float2 bB = two ? cB[(size_t)j2 * 16 + 1] : bA;
        float2 wAl = cA[(size_t)j * 64 + lane];
        float2 wBl = two ? cA[(size_t)j2 * 64 + lane] : wAl;
        f2 Wr, Wi, nWi;
        Wr.x = bA.x; Wr.y = bB.x;
        Wi.x = -bA.y; Wi.y = -bB.y;              // W = conj(cis(64k))
        nWi = -Wi;
        f2 hr = 0.f, hi = 0.f;                   // packed Horner: lane0=binA, lane1=binB
#pragma unroll
        for (int i = 15; i >= 0; --i) {
            f2 xx; xx.x = xr[i]; xx.y = xr[i];
            f2 tmp = nWi * hi + xx;              // pk_fma
            f2 nr = Wr * hr + tmp;               // pk_fma
            hi = Wi * hr + Wr * hi;
            hr = nr;
        }
        f2 wlc, wls;
        wlc.x = wAl.x; wlc.y = wBl.x;
        wls.x = wAl.y; wls.y = wBl.y;
        f2 re = hr * wlc + hi * wls;
        f2 im = hi * wlc - hr * wls;
        float reA = re.x, imA = im.x, reB = re.y, imB = im.y;
#pragma unroll
        for (int m = 32; m >= 1; m >>= 1) {
            reA += __shfl_xor(reA, m, 64);
            imA += __shfl_xor(imA, m, 64);
            reB += __shfl_xor(reB, m, 64);
            imB += __shfl_xor(imB, m, 64);
        }
        if (lane == 0) {
            Hout[j] = make_float2(reA, imA);
            if (two) Hout[j2] = make_float2(reB, imB);
        }
    }
}

// ---------------- analysis (block 0 only): sparse DFT of each 1024-sample half-frame ----------------
__global__ __launch_bounds__(256, 8) void analysis_kernel(
    const float* __restrict__ x, const int* __restrict__ counts,
    const float2* __restrict__ cisA, const float2* __restrict__ cisB,
    float2* __restrict__ H, int iblk, int kmax)
{
    int wg = blockIdx.x;
    int b = wg >> 8, h = wg & 255;
    int tid = threadIdx.x;
    int lane = tid & 63, w = tid >> 6;
    int K = counts[iblk];
    const float* xb = x + (size_t)b * TT + (size_t)h * STEP;
    float xr[16];
#pragma unroll
    for (int i = 0; i < 16; ++i) xr[i] = xb[lane + (i << 6)];
    const float2* cA = cisA + (size_t)iblk * kmax * 64;
    const float2* cB = cisB + (size_t)iblk * kmax * 16;
    float2* Hout = H + (size_t)(b * FRM + h) * K;
    half_dft(xr, K, cA, cB, Hout, lane, w);
}

// accumulate 4 samples for one (seg, bin): acc_i += up*c_i + vp*s_i
__device__ __forceinline__ void acc4(
    f2& q0, f2& q1, f2& q2, f2& q3, float4 e, float4 a0, float4 a1)
{
    f2 up; up.x = e.x; up.y = e.y;
    f2 vp; vp.x = e.z; vp.y = e.w;
    q0 = up * a0.x + q0; q0 = vp * a0.y + q0;
    q1 = up * a0.z + q1; q1 = vp * a0.w + q1;
    q2 = up * a1.x + q2; q2 = vp * a1.y + q2;
    q3 = up * a1.z + q3; q3 = vp * a1.w + q3;
}

// ---------------- fused scan + synthesis (SEGS=4/wg) + next-block analysis ----------------
// Scan dispatches eliminated: each wg computes its own O-prefix from raw H via the
// (round-5-proven) wave shuffle-scan -- 4 frames/lane, ratio t^4, carry t^(c+1) -- and
// extracts frames s0-1..s0+3 via readlane (s0%4==0 -> lane s0/4) into LDS. Prefix only
// reads lanes <= target, so values are bit-identical across wgs regardless of zeroed
// tails. Removes 4 kernel dispatches + 4 graph-node boundaries (~4-6us each measured
// as the residue in rounds 2-5). Synth core unchanged (proven round-3 structure).
__global__ __launch_bounds__(256, 5) void fused_synth_kernel(
    const float2* __restrict__ H, float2* __restrict__ H2,
    const float2* __restrict__ cisA, const float2* __restrict__ cisB,
    const int* __restrict__ counts, const int* __restrict__ bins,
    const float* __restrict__ tvals, const float* __restrict__ gains,
    const float* __restrict__ wmix, const float* __restrict__ hann,
    const float* __restrict__ x, float* __restrict__ dout,
    int iblk, int do_an, int kmax)
{
    // union: rc (synth, 1024 f4) overlaps ystage (1088 f4); part/Olds above both
    __shared__ float4 smem[1216];                 // 19456 B
    float4* rc = smem;                            // [SEGS][KC][16] float4 = 16 KB
    float*  ystage = (float*)smem;                // [SEGS][16][YPAD] floats = 17408 B
    float4* part = smem + 1088;                   // [2][4][16] float4 = 2 KB
    float2* Olds = (float2*)(smem + 1088);        // [KC][5] float2 = 640 B (synth phase only)

    int wg = blockIdx.x;
    int b = wg >> 6, s0 = (wg & 63) << 2;
    int tid = threadIdx.x;
    int n1 = tid << 2;
    int q = tid >> 4;            // [0,16)
    int m = (tid & 15) << 2;     // [0,64) step 4

    int K = counts[iblk];
    const int* bl = bins + iblk * NC;
    const float* tv_ = tvals + iblk * NC;
    const float2* Hb0 = H + (size_t)b * FRM * K;
    const float2* cA0 = cisA + (size_t)iblk * kmax * 64;
    const float2* cB0 = cisB + (size_t)iblk * kmax * 16;

    f2 p00 = 0.f, p01 = 0.f, p02 = 0.f, p03 = 0.f;   // seg s0
    f2 p10 = 0.f, p11 = 0.f, p12 = 0.f, p13 = 0.f;   // seg s0+1
    f2 p20 = 0.f, p21 = 0.f, p22 = 0.f, p23 = 0.f;   // seg s0+2
    f2 p30 = 0.f, p31 = 0.f, p32 = 0.f, p33 = 0.f;   // seg s0+3

    for (int c0 = 0; c0 < K; c0 += KC) {
        int cs = (K - c0 < KC) ? (K - c0) : KC;
        {   // prologue: per-wg prefix scan of H -> O at frames s0-1..s0+3, into Olds
            int wv = tid >> 6, lane = tid & 63;
            int mi = s0 >> 2;                     // extraction lane (s0 % 4 == 0)
            int fmax = s0 + 4;                    // deepest H frame needed
            int f0 = lane << 2;
#pragma unroll
            for (int i5 = 0; i5 < 4; ++i5) {
                int sl = wv + (i5 << 2);          // slot in [0,16)
                int jj = c0 + ((sl < cs) ? sl : (cs - 1));
                float t = tv_[jj];
                int k = bl[jj];
                float sgn = (k & 1) ? -t : t;
                const float2* Hj = Hb0 + jj;
                float2 z2 = make_float2(0.f, 0.f);
                float2 h0 = (f0     <= fmax) ? Hj[(size_t)(f0    ) * K] : z2;
                float2 h1 = (f0 + 1 <= fmax) ? Hj[(size_t)(f0 + 1) * K] : z2;
                float2 h2 = (f0 + 2 <= fmax) ? Hj[(size_t)(f0 + 2) * K] : z2;
                float2 h3 = (f0 + 3 <= fmax) ? Hj[(size_t)(f0 + 3) * K] : z2;
                float h4x = __shfl_down(h0.x, 1, 64);     // frame f0+4 = neighbor's h0
                float h4y = __shfl_down(h0.y, 1, 64);
                if (lane == 63) { h4x = 0.f; h4y = 0.f; } // frame 256 = zero pad half
                // a_c = t*h_c + sgn*h_{c+1}
                float ax0 = fmaf(sgn, h1.x, h0.x * t), ay0 = fmaf(sgn, h1.y, h0.y * t);
                float ax1 = fmaf(sgn, h2.x, h1.x * t), ay1 = fmaf(sgn, h2.y, h1.y * t);
                float ax2 = fmaf(sgn, h3.x, h2.x * t), ay2 = fmaf(sgn, h3.y, h2.y * t);
                float ax3 = fmaf(sgn, h4x,  h3.x * t), ay3 = fmaf(sgn, h4y,  h3.y * t);
                // in-lane inclusive
                float Ax0 = ax0,               Ay0 = ay0;
                float Ax1 = fmaf(t, Ax0, ax1), Ay1 = fmaf(t, Ay0, ay1);
                float Ax2 = fmaf(t, Ax1, ax2), Ay2 = fmaf(t, Ay1, ay2);
                float Ax3 = fmaf(t, Ax2, ax3), Ay3 = fmaf(t, Ay2, ay3);
                // wave scan over lane totals, ratio t^4
                float t2 = t * t, t4 = t2 * t2, t3 = t2 * t;
                float Px = Ax3, Py = Ay3;
                float ww = t4;
#pragma unroll
                for (int d = 1; d <= 32; d <<= 1) {
                    float ux = __shfl_up(Px, d, 64);
                    float uy = __shfl_up(Py, d, 64);
                    if (lane >= d) { Px = fmaf(ww, ux, Px); Py = fmaf(ww, uy, Py); }
                    ww *= ww;
                }
                float Cx = __shfl_up(Px, 1, 64);
                float Cy = __shfl_up(Py, 1, 64);
                if (lane == 0) { Cx = 0.f; Cy = 0.f; }
                float Ox0 = fmaf(t,  Cx, Ax0), Oy0 = fmaf(t,  Cy, Ay0);
                float Ox1 = fmaf(t2, Cx, Ax1), Oy1 = fmaf(t2, Cy, Ay1);
                float Ox2 = fmaf(t3, Cx, Ax2), Oy2 = fmaf(t3, Cy, Ay2);
                float Ox3 = fmaf(t4, Cx, Ax3), Oy3 = fmaf(t4, Cy, Ay3);
                // extract frames s0-1 (lane mi-1, elem3) and s0..s0+3 (lane mi, elem0..3)
                float Omx = (s0 > 0) ? rl(Ox3, mi - 1) : 0.f;
                float Omy = (s0 > 0) ? rl(Oy3, mi - 1) : 0.f;
                float E0x = rl(Ox0, mi), E0y = rl(Oy0, mi);
                float E1x = rl(Ox1, mi), E1y = rl(Oy1, mi);
                float E2x = rl(Ox2, mi), E2y = rl(Oy2, mi);
                float E3x = rl(Ox3, mi), E3y = rl(Oy3, mi);
                if (lane == 0) {
                    Olds[sl * 5 + 0] = make_float2(Omx, Omy);
                    Olds[sl * 5 + 1] = make_float2(E0x, E0y);
                    Olds[sl * 5 + 2] = make_float2(E1x, E1y);
                    Olds[sl * 5 + 3] = make_float2(E2x, E2y);
                    Olds[sl * 5 + 4] = make_float2(E3x, E3y);
                }
            }
        }
        __syncthreads();
        {   // build rc: 4 threads per (seg,j), each does 4 q-entries
            int flat = tid >> 2;                  // 0..63 = seg*KC + j
            int seg = flat >> 4;
            int j = flat & 15;
            int jj = c0 + ((j < cs) ? j : (cs - 1));
            int q0 = (tid & 3) << 2;
            int k = bl[jj];
            float g = ((k == 0) || (k == 1024)) ? (1.0f / 2048.0f) : (2.0f / 2048.0f);
            float sg = (k & 1) ? -g : g;
            float2 o1 = Olds[j * 5 + 1 + seg];    // O at frame s0+seg
            float2 om = Olds[j * 5 + seg];        // O at frame s0+seg-1
            float c2r = om.x * sg, c2i = om.y * sg;
            f2 u; u.x = c2r;  u.y = o1.x * g - c2r;
            f2 v; v.x = -c2i; v.y = -(o1.y * g - c2i);
            const float2* bqp = cB0 + (size_t)jj * 16 + q0;
#pragma unroll
            for (int e = 0; e < 4; ++e) {
                float2 bq = bqp[e];
                f2 up = u * bq.x + v * bq.y;
                f2 vp = v * bq.x - u * bq.y;
                rc[(flat << 4) + q0 + e] = make_float4(up.x, up.y, vp.x, vp.y);
            }
        }
        __syncthreads();
        const float2* cAj = cA0 + ((size_t)c0 << 6) + m;
        const float4* rcq = rc + q;
        int jj = 0;
        for (; jj + 2 <= cs; jj += 2) {
            float4 a00 = *(const float4*)(cAj);
            float4 a01 = *(const float4*)(cAj + 2);
            float4 a10 = *(const float4*)(cAj + 64);
            float4 a11 = *(const float4*)(cAj + 66);
            cAj += 128;
            {   // seg 0
                float4 e0 = rcq[(0 * KC + jj) << 4];
                float4 e1 = rcq[(0 * KC + jj + 1) << 4];
                acc4(p00, p01, p02, p03, e0, a00, a01);
                acc4(p00, p01, p02, p03, e1, a10, a11);
            }
            {   // seg 1
                float4 e0 = rcq[(1 * KC + jj) << 4];
                float4 e1 = rcq[(1 * KC + jj + 1) << 4];
                acc4(p10, p11, p12, p13, e0, a00, a01);
                acc4(p10, p11, p12, p13, e1, a10, a11);
            }
            {   // seg 2
                float4 e0 = rcq[(2 * KC + jj) << 4];
                float4 e1 = rcq[(2 * KC + jj + 1) << 4];
                acc4(p20, p21, p22, p23, e0, a00, a01);
                acc4(p20, p21, p22, p23, e1, a10, a11);
            }
            {   // seg 3
                float4 e0 = rcq[(3 * KC + jj) << 4];
                float4 e1 = rcq[(3 * KC + jj + 1) << 4];
                acc4(p30, p31, p32, p33, e0, a00, a01);
                acc4(p30, p31, p32, p33, e1, a10, a11);
            }
        }
        if (jj < cs) {
            float4 a0 = *(const float4*)(cAj);
            float4 a1 = *(const float4*)(cAj + 2);
            float4 e0 = rcq[(0 * KC + jj) << 4];
            float4 e1 = rcq[(1 * KC + jj) << 4];
            float4 e2 = rcq[(2 * KC + jj) << 4];
            float4 e3 = rcq[(3 * KC + jj) << 4];
            acc4(p00, p01, p02, p03, e0, a0, a1);
            acc4(p10, p11, p12, p13, e1, a0, a1);
            acc4(p20, p21, p22, p23, e2, a0, a1);
            acc4(p30, p31, p32, p33, e3, a0, a1);
        }
        __syncthreads();
    }

    // epilogue: per seg, load prev, tanh, mix, store, stage y (regs die per-seg)
    size_t base0 = (size_t)b * TT + ((size_t)s0 << 10) + (size_t)n1;
    const float* prevsrc = (iblk == 0) ? x : dout;
    float4 hv = *(const float4*)(hann + n1);
    float gain = gains[iblk];
    float wsel = (iblk == 0) ? wmix[0] : 1.0f;
    float wn = wmix[iblk + 1];
    int cw = n1 >> 6, off = n1 & 63;

#define SEG_EPI(s, A0, A1, A2, A3)                                              \
    {                                                                           \
        float4 pv = *(const float4*)(prevsrc + base0 + ((size_t)(s) << 10));    \
        float4 yv;                                                              \
        yv.x = tanh_fast(fmaf(hv.x, A0.y, A0.x) * gain);                        \
        yv.y = tanh_fast(fmaf(hv.y, A1.y, A1.x) * gain);                        \
        yv.z = tanh_fast(fmaf(hv.z, A2.y, A2.x) * gain);                        \
        yv.w = tanh_fast(fmaf(hv.w, A3.y, A3.x) * gain);                        \
        float4 dv;                                                              \
        dv.x = fmaf(wsel, pv.x, wn * yv.x);                                     \
        dv.y = fmaf(wsel, pv.y, wn * yv.y);                                     \
        dv.z = fmaf(wsel, pv.z, wn * yv.z);                                     \
        dv.w = fmaf(wsel, pv.w, wn * yv.w);                                     \
        *(float4*)(dout + base0 + ((size_t)(s) << 10)) = dv;                    \
        if (do_an) *(float4*)(ystage + (s) * 16 * YPAD + cw * YPAD + off) = yv; \
    }

    SEG_EPI(0, p00, p01, p02, p03)
    SEG_EPI(1, p10, p11, p12, p13)
    SEG_EPI(2, p20, p21, p22, p23)
    SEG_EPI(3, p30, p31, p32, p33)
#undef SEG_EPI

    if (do_an) {
        __syncthreads();
        int K2 = counts[iblk + 1];
        if (K2 > 0) {
            const float2* cA2 = cisA + (size_t)(iblk + 1) * kmax * 64;
            const float2* cB2 = cisB + (size_t)(iblk + 1) * kmax * 16;
            int jloc = tid & 15, c = tid >> 4;
            int lane = tid & 63, wv = tid >> 6;
            const float4* yp0 = (const float4*)(ystage + c * YPAD);
            const float4* yp1 = (const float4*)(ystage + 16 * YPAD + c * YPAD);
            const float4* yp2 = (const float4*)(ystage + 32 * YPAD + c * YPAD);
            const float4* yp3 = (const float4*)(ystage + 48 * YPAD + c * YPAD);
            for (int jb = 0; jb < K2; jb += 16) {
                int j = jb + jloc;
                int js = (j < K2) ? j : (K2 - 1);
                float2 w1 = cA2[(size_t)js * 64 + 1];   // cis(k)
                float Wr = w1.x, Wi = -w1.y, nWi = w1.y;
                f2 hrA = 0.f, hiA = 0.f;                // packed (seg0, seg1)
                f2 hrB = 0.f, hiB = 0.f;                // packed (seg2, seg3)
#pragma unroll
                for (int i4 = 15; i4 >= 0; --i4) {
                    float4 ya = yp0[i4];
                    float4 yb = yp1[i4];
                    float4 yc = yp2[i4];
                    float4 yd = yp3[i4];
#define HSTEP(CC)                                                                   \
                    { f2 yy; yy.x = ya.CC; yy.y = yb.CC;                            \
                      f2 t = hiA * nWi + yy; f2 nr = hrA * Wr + t;                  \
                      hiA = hrA * Wi + hiA * Wr; hrA = nr; }                        \
                    { f2 yy; yy.x = yc.CC; yy.y = yd.CC;                            \
                      f2 t = hiB * nWi + yy; f2 nr = hrB * Wr + t;                  \
                      hiB = hrB * Wi + hiB * Wr; hrB = nr; }
                    HSTEP(w)
                    HSTEP(z)
                    HSTEP(y)
                    HSTEP(x)
#undef HSTEP
                }
                float2 bq = cB2[(size_t)js * 16 + c];   // rotate by cis(-64kc)
                f2 reA = hrA * bq.x + hiA * bq.y;
                f2 imA = hiA * bq.x - hrA * bq.y;
                f2 reB = hrB * bq.x + hiB * bq.y;
                f2 imB = hiB * bq.x - hrB * bq.y;
                // reduce over c within wave: lanes differing in bits 4,5 share jloc
                float4 prA = make_float4(reA.x, imA.x, reA.y, imA.y);
                float4 prB = make_float4(reB.x, imB.x, reB.y, imB.y);
#pragma unroll
                for (int d = 16; d <= 32; d <<= 1) {
                    prA.x += __shfl_xor(prA.x, d, 64);
                    prA.y += __shfl_xor(prA.y, d, 64);
                    prA.z += __shfl_xor(prA.z, d, 64);
                    prA.w += __shfl_xor(prA.w, d, 64);
                    prB.x += __shfl_xor(prB.x, d, 64);
                    prB.y += __shfl_xor(prB.y, d, 64);
                    prB.z += __shfl_xor(prB.z, d, 64);
                    prB.w += __shfl_xor(prB.w, d, 64);
                }
                if (lane < 16) {
                    part[wv * 16 + lane] = prA;          // pair (seg0,seg1)
                    part[64 + wv * 16 + lane] = prB;     // pair (seg2,seg3)
                }
                __syncthreads();
                if (tid < 32) {
                    int sel = tid >> 4, t = tid & 15;
                    int j2 = jb + t;
                    if (j2 < K2) {
                        const float4* pp = part + sel * 64;
                        float4 a0 = pp[t];
                        float4 a1 = pp[16 + t];
                        float4 a2 = pp[32 + t];
                        float4 a3 = pp[48 + t];
                        float4 acc;
                        acc.x = (a0.x + a1.x) + (a2.x + a3.x);
                        acc.y = (a0.y + a1.y) + (a2.y + a3.y);
                        acc.z = (a0.z + a1.z) + (a2.z + a3.z);
                        acc.w = (a0.w + a1.w) + (a2.w + a3.w);
                        H2[(size_t)(b * FRM + s0 + sel * 2) * K2 + j2] = make_float2(acc.x, acc.y);
                        H2[(size_t)(b * FRM + s0 + sel * 2 + 1) * K2 + j2] = make_float2(acc.z, acc.w);
                    }
                }
                __syncthreads();
            }
        }
    }
}

extern "C" void kernel_launch(void* const* d_in, const int* in_sizes, int n_in,
                              void* d_out, int out_size, void* d_ws, size_t ws_size,
                              hipStream_t stream)
{
    const float* x         = (const float*)d_in[0];
    const float* transfers = (const float*)d_in[1];
    const float* gains     = (const float*)d_in[2];
    const float* mixer     = (const float*)d_in[3];
    float* dout = (float*)d_out;

    uint8_t* ws = (uint8_t*)d_ws;
    int*   counts = (int*)ws;                          // 16 B
    int*   bins   = (int*)(ws + 64);                   // 4*1025*4 = 16400 B
    float* tvals  = (float*)(ws + 64 + 16400);         // 16400 B
    float* wmix   = (float*)(ws + 64 + 16400 + 16400); // 20 B
    float* hann   = (float*)(ws + 36864);              // 1024 floats
    const size_t HDR = 65536;

    // per-k bytes: two ping-pong H buffers (2*BAT*FRM*8) + cisA (NB*64*8) + cisB (NB*16*8)
    long long perk = 2LL * BAT * FRM * 8 + (long long)NB * 80 * 8;
    long long km = ((long long)ws_size - (long long)HDR) / perk;
    int kmax = (int)((km < 1) ? 1 : ((km > NC) ? NC : km));
    float2* S0 = (float2*)(ws + HDR);
    float2* S1 = S0 + (size_t)BAT * FRM * kmax;
    float2* cisA = S1 + (size_t)BAT * FRM * kmax;      // NB * kmax * 64 float2
    float2* cisB = cisA + (size_t)NB * kmax * 64;      // NB * kmax * 16 float2

    setup_kernel<<<NB, 1024, 0, stream>>>(transfers, mixer, counts, bins, tvals, wmix, hann,
                                          cisA, cisB, kmax);
    analysis_kernel<<<BAT * FRM, 256, 0, stream>>>(x, counts, cisA, cisB, S0, 0, kmax);

    float2* cur = S0;
    float2* nxt = S1;
    for (int i = 0; i < NB; ++i) {
        fused_synth_kernel<<<BAT * (FRM / SEGS), 256, 0, stream>>>(cur, nxt, cisA, cisB, counts,
                                                                   bins, tvals, gains, wmix, hann,
                                                                   x, dout, i,
                                                                   (i < NB - 1) ? 1 : 0, kmax);
        float2* t = cur; cur = nxt; nxt = t;
    }
}

// Round 7
// 246.586 us; speedup vs baseline: 1.1978x; 1.1978x over previous
//
#include <hip/hip_runtime.h>
#include <math.h>
#include <stdint.h>

#define NB   4
#define NC   1025
#define WSZ  2048
#define STEP 1024
#define FRM  256
#define BAT  32
#define TT   262144
#define SEGS 4       // segments (frames) per workgroup in fused synth
#define KC   16      // bin chunk per rc-build in the synth kernel
#define YPAD 68      // floats per 64-sample ystage chunk (+4 pad: conflict-free strides)

// 1/2048 (exact): phases are integers mod 2048 -> revolutions for v_sin/v_cos
#define RREV (1.0f / 2048.0f)

typedef float f2 __attribute__((ext_vector_type(2)));

__device__ __forceinline__ float tanh_fast(float z) {
    float e = __expf(2.0f * z);
    return 1.0f - 2.0f / (e + 1.0f);   // exact tanh identity; inf/0 saturate to +/-1
}

// hardware cis: idx taken mod 2048, argument in revolutions (exact, no range reduction)
__device__ __forceinline__ void cis_rev(int idx, float* c, float* s) {
    float rev = (float)(idx & 2047) * RREV;
    *c = __builtin_amdgcn_cosf(rev);
    *s = __builtin_amdgcn_sinf(rev);
}

// ---------------- setup + tables fused: compact bins, softmax(mixer), hann, cisA/cisB ----------------
__global__ __launch_bounds__(1024) void setup_kernel(
    const float* __restrict__ transfers, const float* __restrict__ mixer,
    int* __restrict__ counts, int* __restrict__ bins, float* __restrict__ tvals,
    float* __restrict__ wmix, float* __restrict__ hann,
    float2* __restrict__ cisA, float2* __restrict__ cisB, int kmax)
{
    int i = blockIdx.x, tid = threadIdx.x;
    __shared__ int wcnt[16], woff[16];
    __shared__ int sK;
    if (i == 0) {                                   // hann[n] = 0.5 - 0.5 cos(2pi n/2048)
        float cc, ss; cis_rev(tid, &cc, &ss);
        hann[tid] = 0.5f - 0.5f * cc;
    }
    float tv = transfers[i * NC + tid];
    bool nz = (tv != 0.0f);
    unsigned long long mask = __ballot(nz);
    int lane = tid & 63, w = tid >> 6;
    int within = __popcll(mask & ((1ULL << lane) - 1ULL));
    if (lane == 0) wcnt[w] = __popcll(mask);
    __syncthreads();
    if (tid == 0) {
        int acc = 0;
        for (int q = 0; q < 16; ++q) { woff[q] = acc; acc += wcnt[q]; }
        float tvL = transfers[i * NC + 1024];       // tail bin k=1024
        if (tvL != 0.0f && acc < kmax) { bins[i * NC + acc] = 1024; tvals[i * NC + acc] = tvL; acc++; }
        int kk = (acc < kmax) ? acc : kmax;
        counts[i] = kk;
        sK = kk;
        if (i == 0) {                               // softmax of mixer[5]
            float m = mixer[0];
            for (int q = 1; q < 5; ++q) m = fmaxf(m, mixer[q]);
            float e[5], s = 0.f;
            for (int q = 0; q < 5; ++q) { e[q] = __expf(mixer[q] - m); s += e[q]; }
            for (int q = 0; q < 5; ++q) wmix[q] = e[q] / s;
        }
    }
    __syncthreads();
    if (nz) {
        int pos = woff[w] + within;
        if (pos < kmax) { bins[i * NC + pos] = tid; tvals[i * NC + pos] = tv; }
    }
    __syncthreads();                                // bins visible to table phase
    int K = sK;
    // table phase: cisA[i][j][m] = cis(2pi k_j m/2048) m<64; cisB[i][j][q] = cis(2pi k_j 64q/2048) q<16
    for (int flat = tid; flat < K * 80; flat += 1024) {
        int j = flat / 80, r = flat - j * 80;
        int k = bins[i * NC + j];
        if (r < 64) {
            float cc, ss; cis_rev(k * r, &cc, &ss);
            cisA[((size_t)i * kmax + j) * 64 + r] = make_float2(cc, ss);
        } else {
            int q = r - 64;
            float cc, ss; cis_rev(k * 64 * q, &cc, &ss);
            cisB[((size_t)i * kmax + j) * 16 + q] = make_float2(cc, ss);
        }
    }
}

// shared half-frame DFT (standalone analysis of x only): xr[16] per lane (n = lane + 64*i),
// bins j = w, w+4, ... < K; W = conj(cisB[j][1]); final rotate by conj(cisA[j][lane]).
__device__ __forceinline__ void half_dft(
    const float xr[16], int K, const float2* __restrict__ cA,
    const float2* __restrict__ cB, float2* __restrict__ Hout, int lane, int w)
{
    for (int j = w; j < K; j += 8) {
        int j2 = j + 4;
        bool two = (j2 < K);
        float2 bA = cB[(size_t)j * 16 + 1];
        float2 bB = two ? cB[(size_t)j2 * 16 + 1] : bA;
        float2 wAl = cA[(size_t)j * 64 + lane];
        float2 wBl = two ? cA[(size_t)j2 * 64 + lane] : wAl;
        f2 Wr, Wi, nWi;
        Wr.x = bA.x; Wr.y = bB.x;
        Wi.x = -bA.y; Wi.y = -bB.y;              // W = conj(cis(64k))
        nWi = -Wi;
        f2 hr = 0.f, hi = 0.f;                   // packed Horner: lane0=binA, lane1=binB
#pragma unroll
        for (int i = 15; i >= 0; --i) {
            f2 xx; xx.x = xr[i]; xx.y = xr[i];
            f2 tmp = nWi * hi + xx;              // pk_fma
            f2 nr = Wr * hr + tmp;               // pk_fma
            hi = Wi * hr + Wr * hi;
            hr = nr;
        }
        f2 wlc, wls;
        wlc.x = wAl.x; wlc.y = wBl.x;
        wls.x = wAl.y; wls.y = wBl.y;
        f2 re = hr * wlc + hi * wls;
        f2 im = hi * wlc - hr * wls;
        float reA = re.x, imA = im.x, reB = re.y, imB = im.y;
#pragma unroll
        for (int m = 32; m >= 1; m >>= 1) {
            reA += __shfl_xor(reA, m, 64);
            imA += __shfl_xor(imA, m, 64);
            reB += __shfl_xor(reB, m, 64);
            imB += __shfl_xor(imB, m, 64);
        }
        if (lane == 0) {
            Hout[j] = make_float2(reA, imA);
            if (two) Hout[j2] = make_float2(reB, imB);
        }
    }
}

// ---------------- analysis (block 0 only): sparse DFT of each 1024-sample half-frame ----------------
__global__ __launch_bounds__(256, 8) void analysis_kernel(
    const float* __restrict__ x, const int* __restrict__ counts,
    const float2* __restrict__ cisA, const float2* __restrict__ cisB,
    float2* __restrict__ H, int iblk, int kmax)
{
    int wg = blockIdx.x;
    int b = wg >> 8, h = wg & 255;
    int tid = threadIdx.x;
    int lane = tid & 63, w = tid >> 6;
    int K = counts[iblk];
    const float* xb = x + (size_t)b * TT + (size_t)h * STEP;
    float xr[16];
#pragma unroll
    for (int i = 0; i < 16; ++i) xr[i] = xb[lane + (i << 6)];
    const float2* cA = cisA + (size_t)iblk * kmax * 64;
    const float2* cB = cisB + (size_t)iblk * kmax * 16;
    float2* Hout = H + (size_t)(b * FRM + h) * K;
    half_dft(xr, K, cA, cB, Hout, lane, w);
}

// ---------------- scan: S_f = H_f + (-1)^k H_{f+1};  O_f = (S_f + O_{f-1}) * t ----------------
// Wave-autonomous: one 64-lane wave per (b, j). Lane owns 4 consecutive frames
// (in-lane serial recurrence), then a shuffle scan over lane totals with ratio t^4
// (weights by repeated squaring), carry applied as t^(c+1)*C. No LDS, no barriers.
__global__ __launch_bounds__(256) void scan_kernel(
    float2* __restrict__ S, const int* __restrict__ counts,
    const int* __restrict__ bins, const float* __restrict__ tvals, int iblk)
{
    int K = counts[iblk];
    int gw = (blockIdx.x << 2) + (threadIdx.x >> 6);
    int lane = threadIdx.x & 63;
    int b = gw & (BAT - 1), j0 = gw >> 5;
    for (int j = j0; j < K; j += 32) {
        float t = tvals[iblk * NC + j];
        int k = bins[iblk * NC + j];
        float sgn = (k & 1) ? -t : t;
        float2* Sb = S + (size_t)b * FRM * K + j;
        int f0 = lane << 2;
        // load h1[0..3] and the successor h1 of frame f0+4 (for h2 of c=3)
        float2 h1_0 = Sb[(size_t)(f0 + 0) * K];
        float2 h1_1 = Sb[(size_t)(f0 + 1) * K];
        float2 h1_2 = Sb[(size_t)(f0 + 2) * K];
        float2 h1_3 = Sb[(size_t)(f0 + 3) * K];
        float2 h1_4 = (f0 + 4 < FRM) ? Sb[(size_t)(f0 + 4) * K] : make_float2(0.f, 0.f);
        // a_c = t*h1_c + sgn*h1_{c+1}
        float ax0 = fmaf(sgn, h1_1.x, h1_0.x * t), ay0 = fmaf(sgn, h1_1.y, h1_0.y * t);
        float ax1 = fmaf(sgn, h1_2.x, h1_1.x * t), ay1 = fmaf(sgn, h1_2.y, h1_1.y * t);
        float ax2 = fmaf(sgn, h1_3.x, h1_2.x * t), ay2 = fmaf(sgn, h1_3.y, h1_2.y * t);
        float ax3 = fmaf(sgn, h1_4.x, h1_3.x * t), ay3 = fmaf(sgn, h1_4.y, h1_3.y * t);
        // in-lane inclusive: A_c = a_c + t*A_{c-1}
        float Ax0 = ax0,                  Ay0 = ay0;
        float Ax1 = fmaf(t, Ax0, ax1),    Ay1 = fmaf(t, Ay0, ay1);
        float Ax2 = fmaf(t, Ax1, ax2),    Ay2 = fmaf(t, Ay1, ay2);
        float Ax3 = fmaf(t, Ax2, ax3),    Ay3 = fmaf(t, Ay2, ay3);
        // wave inclusive scan of lane totals with ratio t^4
        float t2 = t * t, t4 = t2 * t2;
        float Px = Ax3, Py = Ay3;
        float w = t4;
#pragma unroll
        for (int d = 1; d <= 32; d <<= 1) {
            float ux = __shfl_up(Px, d, 64);
            float uy = __shfl_up(Py, d, 64);
            if (lane >= d) { Px = fmaf(w, ux, Px); Py = fmaf(w, uy, Py); }
            w *= w;
        }
        // carry into this lane = inclusive through lane-1
        float Cx = __shfl_up(Px, 1, 64);
        float Cy = __shfl_up(Py, 1, 64);
        if (lane == 0) { Cx = 0.f; Cy = 0.f; }
        // O_c = A_c + t^(c+1)*C
        float t3 = t2 * t;
        Sb[(size_t)(f0 + 0) * K] = make_float2(fmaf(t,  Cx, Ax0), fmaf(t,  Cy, Ay0));
        Sb[(size_t)(f0 + 1) * K] = make_float2(fmaf(t2, Cx, Ax1), fmaf(t2, Cy, Ay1));
        Sb[(size_t)(f0 + 2) * K] = make_float2(fmaf(t3, Cx, Ax2), fmaf(t3, Cy, Ay2));
        Sb[(size_t)(f0 + 3) * K] = make_float2(fmaf(t4, Cx, Ax3), fmaf(t4, Cy, Ay3));
    }
}

// accumulate 4 samples for one (seg, bin): acc_i += up*c_i + vp*s_i
__device__ __forceinline__ void acc4(
    f2& q0, f2& q1, f2& q2, f2& q3, float4 e, float4 a0, float4 a1)
{
    f2 up; up.x = e.x; up.y = e.y;
    f2 vp; vp.x = e.z; vp.y = e.w;
    q0 = up * a0.x + q0; q0 = vp * a0.y + q0;
    q1 = up * a0.z + q1; q1 = vp * a0.w + q1;
    q2 = up * a1.x + q2; q2 = vp * a1.y + q2;
    q3 = up * a1.z + q3; q3 = vp * a1.w + q3;
}

// ---------------- fused synthesis (SEGS=4 segments/wg) + next-block analysis ----------------
// Proven round-3 core. (256,8): force 64-reg allocation so 8 wgs/CU are co-resident.
// At (256,5) the compiler used 72 regs -> 7 wgs/CU cap with an 8 wg/CU grid => every CU
// ran 7 wgs then 1 straggler (measured occupancy 48% ~= (87%+12%)/2, 2x the ideal round
// time). LDS 19456B x 8 = 155.6KB <= 160KB fits. Spill tripwire: WRITE_SIZE must stay
// 33.7MB -- if it grows, the 64-reg cap spilled and this bound must revert.
__global__ __launch_bounds__(256, 8) void fused_synth_kernel(
    const float2* __restrict__ S, float2* __restrict__ H2,
    const float2* __restrict__ cisA, const float2* __restrict__ cisB,
    const int* __restrict__ counts, const int* __restrict__ bins,
    const float* __restrict__ gains, const float* __restrict__ wmix,
    const float* __restrict__ hann, const float* __restrict__ x,
    float* __restrict__ dout, int iblk, int do_an, int kmax)
{
    // union: rc (synth phase, 1024 f4) overlaps ystage (1088 f4); part sits above both
    __shared__ float4 smem[1216];                 // 19456 B
    float4* rc = smem;                            // [SEGS][KC][16] float4 = 16 KB
    float*  ystage = (float*)smem;                // [SEGS][16][YPAD] floats = 17408 B
    float4* part = smem + 1088;                   // [2][4][16] float4 = 2 KB

    int wg = blockIdx.x;
    int b = wg >> 6, s0 = (wg & 63) << 2;
    int tid = threadIdx.x;
    int n1 = tid << 2;
    int q = tid >> 4;            // [0,16)
    int m = (tid & 15) << 2;     // [0,64) step 4

    int K = counts[iblk];
    const int* bl = bins + iblk * NC;
    const float2* Ob = S + (size_t)b * FRM * K;
    const float2* cA0 = cisA + (size_t)iblk * kmax * 64;
    const float2* cB0 = cisB + (size_t)iblk * kmax * 16;

    f2 p00 = 0.f, p01 = 0.f, p02 = 0.f, p03 = 0.f;   // seg s0
    f2 p10 = 0.f, p11 = 0.f, p12 = 0.f, p13 = 0.f;   // seg s0+1
    f2 p20 = 0.f, p21 = 0.f, p22 = 0.f, p23 = 0.f;   // seg s0+2
    f2 p30 = 0.f, p31 = 0.f, p32 = 0.f, p33 = 0.f;   // seg s0+3

    for (int c0 = 0; c0 < K; c0 += KC) {
        int cs = (K - c0 < KC) ? (K - c0) : KC;
        {   // build rc: 4 threads per (seg,j), each does 4 q-entries
            int flat = tid >> 2;                  // 0..63 = seg*KC + j
            int seg = flat >> 4;
            int j = flat & 15;
            int jj = c0 + ((j < cs) ? j : (cs - 1));
            int q0 = (tid & 3) << 2;
            int k = bl[jj];
            float g = ((k == 0) || (k == 1024)) ? (1.0f / 2048.0f) : (2.0f / 2048.0f);
            float sg = (k & 1) ? -g : g;
            int fc = s0 + seg;
            float2 o1 = Ob[(size_t)fc * K + jj];
            float2 om = (fc > 0) ? Ob[(size_t)(fc - 1) * K + jj] : make_float2(0.f, 0.f);
            float c2r = om.x * sg, c2i = om.y * sg;
            f2 u; u.x = c2r;  u.y = o1.x * g - c2r;
            f2 v; v.x = -c2i; v.y = -(o1.y * g - c2i);
            const float2* bqp = cB0 + (size_t)jj * 16 + q0;
#pragma unroll
            for (int e = 0; e < 4; ++e) {
                float2 bq = bqp[e];
                f2 up = u * bq.x + v * bq.y;
                f2 vp = v * bq.x - u * bq.y;
                rc[(flat << 4) + q0 + e] = make_float4(up.x, up.y, vp.x, vp.y);
            }
        }
        __syncthreads();
        const float2* cAj = cA0 + ((size_t)c0 << 6) + m;
        const float4* rcq = rc + q;
        int jj = 0;
        for (; jj + 2 <= cs; jj += 2) {
            float4 a00 = *(const float4*)(cAj);
            float4 a01 = *(const float4*)(cAj + 2);
            float4 a10 = *(const float4*)(cAj + 64);
            float4 a11 = *(const float4*)(cAj + 66);
            cAj += 128;
            {   // seg 0
                float4 e0 = rcq[(0 * KC + jj) << 4];
                float4 e1 = rcq[(0 * KC + jj + 1) << 4];
                acc4(p00, p01, p02, p03, e0, a00, a01);
                acc4(p00, p01, p02, p03, e1, a10, a11);
            }
            {   // seg 1
                float4 e0 = rcq[(1 * KC + jj) << 4];
                float4 e1 = rcq[(1 * KC + jj + 1) << 4];
                acc4(p10, p11, p12, p13, e0, a00, a01);
                acc4(p10, p11, p12, p13, e1, a10, a11);
            }
            {   // seg 2
                float4 e0 = rcq[(2 * KC + jj) << 4];
                float4 e1 = rcq[(2 * KC + jj + 1) << 4];
                acc4(p20, p21, p22, p23, e0, a00, a01);
                acc4(p20, p21, p22, p23, e1, a10, a11);
            }
            {   // seg 3
                float4 e0 = rcq[(3 * KC + jj) << 4];
                float4 e1 = rcq[(3 * KC + jj + 1) << 4];
                acc4(p30, p31, p32, p33, e0, a00, a01);
                acc4(p30, p31, p32, p33, e1, a10, a11);
            }
        }
        if (jj < cs) {
            float4 a0 = *(const float4*)(cAj);
            float4 a1 = *(const float4*)(cAj + 2);
            float4 e0 = rcq[(0 * KC + jj) << 4];
            float4 e1 = rcq[(1 * KC + jj) << 4];
            float4 e2 = rcq[(2 * KC + jj) << 4];
            float4 e3 = rcq[(3 * KC + jj) << 4];
            acc4(p00, p01, p02, p03, e0, a0, a1);
            acc4(p10, p11, p12, p13, e1, a0, a1);
            acc4(p20, p21, p22, p23, e2, a0, a1);
            acc4(p30, p31, p32, p33, e3, a0, a1);
        }
        __syncthreads();
    }

    // epilogue: per seg, load prev, tanh, mix, store, stage y (regs die per-seg)
    size_t base0 = (size_t)b * TT + ((size_t)s0 << 10) + (size_t)n1;
    const float* prevsrc = (iblk == 0) ? x : dout;
    float4 hv = *(const float4*)(hann + n1);
    float gain = gains[iblk];
    float wsel = (iblk == 0) ? wmix[0] : 1.0f;
    float wn = wmix[iblk + 1];
    int cw = n1 >> 6, off = n1 & 63;

#define SEG_EPI(s, A0, A1, A2, A3)                                              \
    {                                                                           \
        float4 pv = *(const float4*)(prevsrc + base0 + ((size_t)(s) << 10));    \
        float4 yv;                                                              \
        yv.x = tanh_fast(fmaf(hv.x, A0.y, A0.x) * gain);                        \
        yv.y = tanh_fast(fmaf(hv.y, A1.y, A1.x) * gain);                        \
        yv.z = tanh_fast(fmaf(hv.z, A2.y, A2.x) * gain);                        \
        yv.w = tanh_fast(fmaf(hv.w, A3.y, A3.x) * gain);                        \
        float4 dv;                                                              \
        dv.x = fmaf(wsel, pv.x, wn * yv.x);                                     \
        dv.y = fmaf(wsel, pv.y, wn * yv.y);                                     \
        dv.z = fmaf(wsel, pv.z, wn * yv.z);                                     \
        dv.w = fmaf(wsel, pv.w, wn * yv.w);                                     \
        *(float4*)(dout + base0 + ((size_t)(s) << 10)) = dv;                    \
        if (do_an) *(float4*)(ystage + (s) * 16 * YPAD + cw * YPAD + off) = yv; \
    }

    SEG_EPI(0, p00, p01, p02, p03)
    SEG_EPI(1, p10, p11, p12, p13)
    SEG_EPI(2, p20, p21, p22, p23)
    SEG_EPI(3, p30, p31, p32, p33)
#undef SEG_EPI

    if (do_an) {
        __syncthreads();
        int K2 = counts[iblk + 1];
        if (K2 > 0) {
            const float2* cA2 = cisA + (size_t)(iblk + 1) * kmax * 64;
            const float2* cB2 = cisB + (size_t)(iblk + 1) * kmax * 16;
            int jloc = tid & 15, c = tid >> 4;
            int lane = tid & 63, wv = tid >> 6;
            const float4* yp0 = (const float4*)(ystage + c * YPAD);
            const float4* yp1 = (const float4*)(ystage + 16 * YPAD + c * YPAD);
            const float4* yp2 = (const float4*)(ystage + 32 * YPAD + c * YPAD);
            const float4* yp3 = (const float4*)(ystage + 48 * YPAD + c * YPAD);
            for (int jb = 0; jb < K2; jb += 16) {
                int j = jb + jloc;
                int js = (j < K2) ? j : (K2 - 1);
                float2 w1 = cA2[(size_t)js * 64 + 1];   // cis(k)
                float Wr = w1.x, Wi = -w1.y, nWi = w1.y;
                f2 hrA = 0.f, hiA = 0.f;                // packed (seg0, seg1)
                f2 hrB = 0.f, hiB = 0.f;                // packed (seg2, seg3)
#pragma unroll
                for (int i4 = 15; i4 >= 0; --i4) {
                    float4 ya = yp0[i4];
                    float4 yb = yp1[i4];
                    float4 yc = yp2[i4];
                    float4 yd = yp3[i4];
#define HSTEP(CC)                                                                   \
                    { f2 yy; yy.x = ya.CC; yy.y = yb.CC;                            \
                      f2 t = hiA * nWi + yy; f2 nr = hrA * Wr + t;                  \
                      hiA = hrA * Wi + hiA * Wr; hrA = nr; }                        \
                    { f2 yy; yy.x = yc.CC; yy.y = yd.CC;                            \
                      f2 t = hiB * nWi + yy; f2 nr = hrB * Wr + t;                  \
                      hiB = hrB * Wi + hiB * Wr; hrB = nr; }
                    HSTEP(w)
                    HSTEP(z)
                    HSTEP(y)
                    HSTEP(x)
#undef HSTEP
                }
                float2 bq = cB2[(size_t)js * 16 + c];   // rotate by cis(-64kc)
                f2 reA = hrA * bq.x + hiA * bq.y;
                f2 imA = hiA * bq.x - hrA * bq.y;
                f2 reB = hrB * bq.x + hiB * bq.y;
                f2 imB = hiB * bq.x - hrB * bq.y;
                // reduce over c within wave: lanes differing in bits 4,5 share jloc
                float4 prA = make_float4(reA.x, imA.x, reA.y, imA.y);
                float4 prB = make_float4(reB.x, imB.x, reB.y, imB.y);
#pragma unroll
                for (int d = 16; d <= 32; d <<= 1) {
                    prA.x += __shfl_xor(prA.x, d, 64);
                    prA.y += __shfl_xor(prA.y, d, 64);
                    prA.z += __shfl_xor(prA.z, d, 64);
                    prA.w += __shfl_xor(prA.w, d, 64);
                    prB.x += __shfl_xor(prB.x, d, 64);
                    prB.y += __shfl_xor(prB.y, d, 64);
                    prB.z += __shfl_xor(prB.z, d, 64);
                    prB.w += __shfl_xor(prB.w, d, 64);
                }
                if (lane < 16) {
                    part[wv * 16 + lane] = prA;          // pair (seg0,seg1)
                    part[64 + wv * 16 + lane] = prB;     // pair (seg2,seg3)
                }
                __syncthreads();
                if (tid < 32) {
                    int sel = tid >> 4, t = tid & 15;
                    int j2 = jb + t;
                    if (j2 < K2) {
                        const float4* pp = part + sel * 64;
                        float4 a0 = pp[t];
                        float4 a1 = pp[16 + t];
                        float4 a2 = pp[32 + t];
                        float4 a3 = pp[48 + t];
                        float4 acc;
                        acc.x = (a0.x + a1.x) + (a2.x + a3.x);
                        acc.y = (a0.y + a1.y) + (a2.y + a3.y);
                        acc.z = (a0.z + a1.z) + (a2.z + a3.z);
                        acc.w = (a0.w + a1.w) + (a2.w + a3.w);
                        H2[(size_t)(b * FRM + s0 + sel * 2) * K2 + j2] = make_float2(acc.x, acc.y);
                        H2[(size_t)(b * FRM + s0 + sel * 2 + 1) * K2 + j2] = make_float2(acc.z, acc.w);
                    }
                }
                __syncthreads();
            }
        }
    }
}

extern "C" void kernel_launch(void* const* d_in, const int* in_sizes, int n_in,
                              void* d_out, int out_size, void* d_ws, size_t ws_size,
                              hipStream_t stream)
{
    const float* x         = (const float*)d_in[0];
    const float* transfers = (const float*)d_in[1];
    const float* gains     = (const float*)d_in[2];
    const float* mixer     = (const float*)d_in[3];
    float* dout = (float*)d_out;

    uint8_t* ws = (uint8_t*)d_ws;
    int*   counts = (int*)ws;                          // 16 B
    int*   bins   = (int*)(ws + 64);                   // 4*1025*4 = 16400 B
    float* tvals  = (float*)(ws + 64 + 16400);         // 16400 B
    float* wmix   = (float*)(ws + 64 + 16400 + 16400); // 20 B
    float* hann   = (float*)(ws + 36864);              // 1024 floats
    const size_t HDR = 65536;

    // per-k bytes: two ping-pong S buffers (2*BAT*FRM*8) + cisA (NB*64*8) + cisB (NB*16*8)
    long long perk = 2LL * BAT * FRM * 8 + (long long)NB * 80 * 8;
    long long km = ((long long)ws_size - (long long)HDR) / perk;
    int kmax = (int)((km < 1) ? 1 : ((km > NC) ? NC : km));
    float2* S0 = (float2*)(ws + HDR);
    float2* S1 = S0 + (size_t)BAT * FRM * kmax;
    float2* cisA = S1 + (size_t)BAT * FRM * kmax;      // NB * kmax * 64 float2
    float2* cisB = cisA + (size_t)NB * kmax * 64;      // NB * kmax * 16 float2

    setup_kernel<<<NB, 1024, 0, stream>>>(transfers, mixer, counts, bins, tvals, wmix, hann,
                                          cisA, cisB, kmax);
    analysis_kernel<<<BAT * FRM, 256, 0, stream>>>(x, counts, cisA, cisB, S0, 0, kmax);

    float2* cur = S0;
    float2* nxt = S1;
    for (int i = 0; i < NB; ++i) {
        scan_kernel<<<BAT * 8, 256, 0, stream>>>(cur, counts, bins, tvals, i);
        fused_synth_kernel<<<BAT * (FRM / SEGS), 256, 0, stream>>>(cur, nxt, cisA, cisB, counts, bins,
                                                                   gains, wmix, hann, x, dout, i,
                                                                   (i < NB - 1) ? 1 : 0, kmax);
        float2* t = cur; cur = nxt; nxt = t;
    }
}

// Round 8
// 235.114 us; speedup vs baseline: 1.2562x; 1.0488x over previous
//
#include <hip/hip_runtime.h>
#include <math.h>
#include <stdint.h>

#define NB   4
#define NC   1025
#define WSZ  2048
#define STEP 1024
#define FRM  256
#define BAT  32
#define TT   262144
#define SEGS 4       // segments (frames) per workgroup in fused synth
#define KC   16      // bin chunk per rc-build in the synth kernel
#define YPAD 68      // floats per 64-sample ystage chunk (+4 pad: conflict-free strides)

// 1/2048 (exact): phases are integers mod 2048 -> revolutions for v_sin/v_cos
#define RREV (1.0f / 2048.0f)

typedef float f2 __attribute__((ext_vector_type(2)));

__device__ __forceinline__ float tanh_fast(float z) {
    float e = __expf(2.0f * z);
    return 1.0f - 2.0f / (e + 1.0f);   // exact tanh identity; inf/0 saturate to +/-1
}

// hardware cis: idx taken mod 2048, argument in revolutions (exact, no range reduction)
__device__ __forceinline__ void cis_rev(int idx, float* c, float* s) {
    float rev = (float)(idx & 2047) * RREV;
    *c = __builtin_amdgcn_cosf(rev);
    *s = __builtin_amdgcn_sinf(rev);
}

// ---------------- setup + tables fused: compact bins, softmax(mixer), hann, cisA/cisB ----------------
// (table_kernel folded in: same block owns this block's bins after the barrier; saves one
// dispatch + one graph-node boundary, ~2-3us per round-6 calibration.)
__global__ __launch_bounds__(1024) void setup_kernel(
    const float* __restrict__ transfers, const float* __restrict__ mixer,
    int* __restrict__ counts, int* __restrict__ bins, float* __restrict__ tvals,
    float* __restrict__ wmix, float* __restrict__ hann,
    float2* __restrict__ cisA, float2* __restrict__ cisB, int kmax)
{
    int i = blockIdx.x, tid = threadIdx.x;
    __shared__ int wcnt[16], woff[16];
    __shared__ int sK;
    if (i == 0) {                                   // hann[n] = 0.5 - 0.5 cos(2pi n/2048)
        float cc, ss; cis_rev(tid, &cc, &ss);
        hann[tid] = 0.5f - 0.5f * cc;
    }
    float tv = transfers[i * NC + tid];
    bool nz = (tv != 0.0f);
    unsigned long long mask = __ballot(nz);
    int lane = tid & 63, w = tid >> 6;
    int within = __popcll(mask & ((1ULL << lane) - 1ULL));
    if (lane == 0) wcnt[w] = __popcll(mask);
    __syncthreads();
    if (tid == 0) {
        int acc = 0;
        for (int q = 0; q < 16; ++q) { woff[q] = acc; acc += wcnt[q]; }
        float tvL = transfers[i * NC + 1024];       // tail bin k=1024
        if (tvL != 0.0f && acc < kmax) { bins[i * NC + acc] = 1024; tvals[i * NC + acc] = tvL; acc++; }
        int kk = (acc < kmax) ? acc : kmax;
        counts[i] = kk;
        sK = kk;
        if (i == 0) {                               // softmax of mixer[5]
            float m = mixer[0];
            for (int q = 1; q < 5; ++q) m = fmaxf(m, mixer[q]);
            float e[5], s = 0.f;
            for (int q = 0; q < 5; ++q) { e[q] = __expf(mixer[q] - m); s += e[q]; }
            for (int q = 0; q < 5; ++q) wmix[q] = e[q] / s;
        }
    }
    __syncthreads();
    if (nz) {
        int pos = woff[w] + within;
        if (pos < kmax) { bins[i * NC + pos] = tid; tvals[i * NC + pos] = tv; }
    }
    __syncthreads();                                // bins visible to table phase
    int K = sK;
    // table phase: cisA[i][j][m] = cis(2pi k_j m/2048) m<64; cisB[i][j][q] = cis(2pi k_j 64q/2048) q<16
    for (int flat = tid; flat < K * 80; flat += 1024) {
        int j = flat / 80, r = flat - j * 80;
        int k = bins[i * NC + j];
        if (r < 64) {
            float cc, ss; cis_rev(k * r, &cc, &ss);
            cisA[((size_t)i * kmax + j) * 64 + r] = make_float2(cc, ss);
        } else {
            int q = r - 64;
            float cc, ss; cis_rev(k * 64 * q, &cc, &ss);
            cisB[((size_t)i * kmax + j) * 16 + q] = make_float2(cc, ss);
        }
    }
}

// shared half-frame DFT (standalone analysis of x only): xr[16] per lane (n = lane + 64*i),
// bins j = w, w+4, ... < K; W = conj(cisB[j][1]); final rotate by conj(cisA[j][lane]).
__device__ __forceinline__ void half_dft(
    const float xr[16], int K, const float2* __restrict__ cA,
    const float2* __restrict__ cB, float2* __restrict__ Hout, int lane, int w)
{
    for (int j = w; j < K; j += 8) {
        int j2 = j + 4;
        bool two = (j2 < K);
        float2 bA = cB[(size_t)j * 16 + 1];
        float2 bB = two ? cB[(size_t)j2 * 16 + 1] : bA;
        float2 wAl = cA[(size_t)j * 64 + lane];
        float2 wBl = two ? cA[(size_t)j2 * 64 + lane] : wAl;
        f2 Wr, Wi, nWi;
        Wr.x = bA.x; Wr.y = bB.x;
        Wi.x = -bA.y; Wi.y = -bB.y;              // W = conj(cis(64k))
        nWi = -Wi;
        f2 hr = 0.f, hi = 0.f;                   // packed Horner: lane0=binA, lane1=binB
#pragma unroll
        for (int i = 15; i >= 0; --i) {
            f2 xx; xx.x = xr[i]; xx.y = xr[i];
            f2 tmp = nWi * hi + xx;              // pk_fma
            f2 nr = Wr * hr + tmp;               // pk_fma
            hi = Wi * hr + Wr * hi;
            hr = nr;
        }
        f2 wlc, wls;
        wlc.x = wAl.x; wlc.y = wBl.x;
        wls.x = wAl.y; wls.y = wBl.y;
        f2 re = hr * wlc + hi * wls;
        f2 im = hi * wlc - hr * wls;
        float reA = re.x, imA = im.x, reB = re.y, imB = im.y;
#pragma unroll
        for (int m = 32; m >= 1; m >>= 1) {
            reA += __shfl_xor(reA, m, 64);
            imA += __shfl_xor(imA, m, 64);
            reB += __shfl_xor(reB, m, 64);
            imB += __shfl_xor(imB, m, 64);
        }
        if (lane == 0) {
            Hout[j] = make_float2(reA, imA);
            if (two) Hout[j2] = make_float2(reB, imB);
        }
    }
}

// ---------------- analysis (block 0 only): sparse DFT of each 1024-sample half-frame ----------------
__global__ __launch_bounds__(256, 8) void analysis_kernel(
    const float* __restrict__ x, const int* __restrict__ counts,
    const float2* __restrict__ cisA, const float2* __restrict__ cisB,
    float2* __restrict__ H, int iblk, int kmax)
{
    int wg = blockIdx.x;
    int b = wg >> 8, h = wg & 255;
    int tid = threadIdx.x;
    int lane = tid & 63, w = tid >> 6;
    int K = counts[iblk];
    const float* xb = x + (size_t)b * TT + (size_t)h * STEP;
    float xr[16];
#pragma unroll
    for (int i = 0; i < 16; ++i) xr[i] = xb[lane + (i << 6)];
    const float2* cA = cisA + (size_t)iblk * kmax * 64;
    const float2* cB = cisB + (size_t)iblk * kmax * 16;
    float2* Hout = H + (size_t)(b * FRM + h) * K;
    half_dft(xr, K, cA, cB, Hout, lane, w);
}

// ---------------- scan: S_f = H_f + (-1)^k H_{f+1};  O_f = (S_f + O_{f-1}) * t ----------------
// Constant-coefficient first-order recurrence: in-wave shuffle scan (t^d by squaring)
// + one LDS cross-wave combine. (Exact round-3 version -- best measured total.)
__global__ __launch_bounds__(256) void scan_kernel(
    float2* __restrict__ S, const int* __restrict__ counts,
    const int* __restrict__ bins, const float* __restrict__ tvals, int iblk)
{
    int K = counts[iblk];
    int wg = blockIdx.x;
    int b = wg & (BAT - 1), j0 = wg >> 5;
    int f = threadIdx.x;
    int lane = f & 63, w = f >> 6;
    __shared__ float2 wtot[4];
    for (int j = j0; j < K; j += 32) {
        float t = tvals[iblk * NC + j];
        int k = bins[iblk * NC + j];
        float2* Sb = S + (size_t)b * FRM * K + j;
        float2 h1 = Sb[(size_t)f * K];
        float2 h2 = (f < FRM - 1) ? Sb[(size_t)(f + 1) * K] : make_float2(0.f, 0.f);
        float sgn = (k & 1) ? -t : t;
        float ax = fmaf(sgn, h2.x, h1.x * t);    // a_f = t*S_f
        float ay = fmaf(sgn, h2.y, h1.y * t);
        float td = t;
        float tp0, tp1, tp2, tp3, tp4, tp5;
#pragma unroll
        for (int s = 0; s < 6; ++s) {
            int d = 1 << s;
            if (s == 0) tp0 = td; else if (s == 1) tp1 = td; else if (s == 2) tp2 = td;
            else if (s == 3) tp3 = td; else if (s == 4) tp4 = td; else tp5 = td;
            float bx = __shfl_up(ax, d, 64);
            float by = __shfl_up(ay, d, 64);
            if (lane >= d) { ax = fmaf(td, bx, ax); ay = fmaf(td, by, ay); }
            td *= td;                            // after loop: td = t^64
        }
        if (lane == 63) wtot[w] = make_float2(ax, ay);
        __syncthreads();
        float px = 0.f, py = 0.f;
#pragma unroll
        for (int w2 = 0; w2 < 3; ++w2) {
            if (w2 < w) {
                float2 v = wtot[w2];
                px = fmaf(px, td, v.x);
                py = fmaf(py, td, v.y);
            }
        }
        int n = lane + 1;
        float fac = (n & 64) ? td : 1.0f;
        if (n & 1)  fac *= tp0;
        if (n & 2)  fac *= tp1;
        if (n & 4)  fac *= tp2;
        if (n & 8)  fac *= tp3;
        if (n & 16) fac *= tp4;
        if (n & 32) fac *= tp5;
        ax = fmaf(fac, px, ax);
        ay = fmaf(fac, py, ay);
        Sb[(size_t)f * K] = make_float2(ax, ay);
        __syncthreads();                         // wtot reused next j-iteration
    }
}

// accumulate 4 samples for one (seg, bin): acc_i += up*c_i + vp*s_i
__device__ __forceinline__ void acc4(
    f2& q0, f2& q1, f2& q2, f2& q3, float4 e, float4 a0, float4 a1)
{
    f2 up; up.x = e.x; up.y = e.y;
    f2 vp; vp.x = e.z; vp.y = e.w;
    q0 = up * a0.x + q0; q0 = vp * a0.y + q0;
    q1 = up * a0.z + q1; q1 = vp * a0.w + q1;
    q2 = up * a1.x + q2; q2 = vp * a1.y + q2;
    q3 = up * a1.z + q3; q3 = vp * a1.w + q3;
}

// ---------------- fused synthesis (SEGS=4 segments/wg) + next-block analysis ----------------
// EXACT round-3 kernel (best measured: 234.2us total). (256,5) is the sweet spot:
// (256,4)=88 regs was fine but 5 waves; (256,6)=72 regs neutral; (256,8)=64 regs
// REGRESSED +2.7us/dispatch (round 7 -- reg cap too tight, spill/serialize). Do not
// re-tighten. Structural rewrites all measured worse: barrier-free (R4 +43%), in-kernel
// scan (R6 +50%), 64-reg cap (R7 +6%).
__global__ __launch_bounds__(256, 5) void fused_synth_kernel(
    const float2* __restrict__ S, float2* __restrict__ H2,
    const float2* __restrict__ cisA, const float2* __restrict__ cisB,
    const int* __restrict__ counts, const int* __restrict__ bins,
    const float* __restrict__ gains, const float* __restrict__ wmix,
    const float* __restrict__ hann, const float* __restrict__ x,
    float* __restrict__ dout, int iblk, int do_an, int kmax)
{
    // union: rc (synth phase, 1024 f4) overlaps ystage (1088 f4); part sits above both
    __shared__ float4 smem[1216];                 // 19456 B
    float4* rc = smem;                            // [SEGS][KC][16] float4 = 16 KB
    float*  ystage = (float*)smem;                // [SEGS][16][YPAD] floats = 17408 B
    float4* part = smem + 1088;                   // [2][4][16] float4 = 2 KB

    int wg = blockIdx.x;
    int b = wg >> 6, s0 = (wg & 63) << 2;
    int tid = threadIdx.x;
    int n1 = tid << 2;
    int q = tid >> 4;            // [0,16)
    int m = (tid & 15) << 2;     // [0,64) step 4

    int K = counts[iblk];
    const int* bl = bins + iblk * NC;
    const float2* Ob = S + (size_t)b * FRM * K;
    const float2* cA0 = cisA + (size_t)iblk * kmax * 64;
    const float2* cB0 = cisB + (size_t)iblk * kmax * 16;

    f2 p00 = 0.f, p01 = 0.f, p02 = 0.f, p03 = 0.f;   // seg s0
    f2 p10 = 0.f, p11 = 0.f, p12 = 0.f, p13 = 0.f;   // seg s0+1
    f2 p20 = 0.f, p21 = 0.f, p22 = 0.f, p23 = 0.f;   // seg s0+2
    f2 p30 = 0.f, p31 = 0.f, p32 = 0.f, p33 = 0.f;   // seg s0+3

    for (int c0 = 0; c0 < K; c0 += KC) {
        int cs = (K - c0 < KC) ? (K - c0) : KC;
        {   // build rc: 4 threads per (seg,j), each does 4 q-entries
            int flat = tid >> 2;                  // 0..63 = seg*KC + j
            int seg = flat >> 4;
            int j = flat & 15;
            int jj = c0 + ((j < cs) ? j : (cs - 1));
            int q0 = (tid & 3) << 2;
            int k = bl[jj];
            float g = ((k == 0) || (k == 1024)) ? (1.0f / 2048.0f) : (2.0f / 2048.0f);
            float sg = (k & 1) ? -g : g;
            int fc = s0 + seg;
            float2 o1 = Ob[(size_t)fc * K + jj];
            float2 om = (fc > 0) ? Ob[(size_t)(fc - 1) * K + jj] : make_float2(0.f, 0.f);
            float c2r = om.x * sg, c2i = om.y * sg;
            f2 u; u.x = c2r;  u.y = o1.x * g - c2r;
            f2 v; v.x = -c2i; v.y = -(o1.y * g - c2i);
            const float2* bqp = cB0 + (size_t)jj * 16 + q0;
#pragma unroll
            for (int e = 0; e < 4; ++e) {
                float2 bq = bqp[e];
                f2 up = u * bq.x + v * bq.y;
                f2 vp = v * bq.x - u * bq.y;
                rc[(flat << 4) + q0 + e] = make_float4(up.x, up.y, vp.x, vp.y);
            }
        }
        __syncthreads();
        const float2* cAj = cA0 + ((size_t)c0 << 6) + m;
        const float4* rcq = rc + q;
        int jj = 0;
        for (; jj + 2 <= cs; jj += 2) {
            float4 a00 = *(const float4*)(cAj);
            float4 a01 = *(const float4*)(cAj + 2);
            float4 a10 = *(const float4*)(cAj + 64);
            float4 a11 = *(const float4*)(cAj + 66);
            cAj += 128;
            {   // seg 0
                float4 e0 = rcq[(0 * KC + jj) << 4];
                float4 e1 = rcq[(0 * KC + jj + 1) << 4];
                acc4(p00, p01, p02, p03, e0, a00, a01);
                acc4(p00, p01, p02, p03, e1, a10, a11);
            }
            {   // seg 1
                float4 e0 = rcq[(1 * KC + jj) << 4];
                float4 e1 = rcq[(1 * KC + jj + 1) << 4];
                acc4(p10, p11, p12, p13, e0, a00, a01);
                acc4(p10, p11, p12, p13, e1, a10, a11);
            }
            {   // seg 2
                float4 e0 = rcq[(2 * KC + jj) << 4];
                float4 e1 = rcq[(2 * KC + jj + 1) << 4];
                acc4(p20, p21, p22, p23, e0, a00, a01);
                acc4(p20, p21, p22, p23, e1, a10, a11);
            }
            {   // seg 3
                float4 e0 = rcq[(3 * KC + jj) << 4];
                float4 e1 = rcq[(3 * KC + jj + 1) << 4];
                acc4(p30, p31, p32, p33, e0, a00, a01);
                acc4(p30, p31, p32, p33, e1, a10, a11);
            }
        }
        if (jj < cs) {
            float4 a0 = *(const float4*)(cAj);
            float4 a1 = *(const float4*)(cAj + 2);
            float4 e0 = rcq[(0 * KC + jj) << 4];
            float4 e1 = rcq[(1 * KC + jj) << 4];
            float4 e2 = rcq[(2 * KC + jj) << 4];
            float4 e3 = rcq[(3 * KC + jj) << 4];
            acc4(p00, p01, p02, p03, e0, a0, a1);
            acc4(p10, p11, p12, p13, e1, a0, a1);
            acc4(p20, p21, p22, p23, e2, a0, a1);
            acc4(p30, p31, p32, p33, e3, a0, a1);
        }
        __syncthreads();
    }

    // epilogue: per seg, load prev, tanh, mix, store, stage y (regs die per-seg)
    size_t base0 = (size_t)b * TT + ((size_t)s0 << 10) + (size_t)n1;
    const float* prevsrc = (iblk == 0) ? x : dout;
    float4 hv = *(const float4*)(hann + n1);
    float gain = gains[iblk];
    float wsel = (iblk == 0) ? wmix[0] : 1.0f;
    float wn = wmix[iblk + 1];
    int cw = n1 >> 6, off = n1 & 63;

#define SEG_EPI(s, A0, A1, A2, A3)                                              \
    {                                                                           \
        float4 pv = *(const float4*)(prevsrc + base0 + ((size_t)(s) << 10));    \
        float4 yv;                                                              \
        yv.x = tanh_fast(fmaf(hv.x, A0.y, A0.x) * gain);                        \
        yv.y = tanh_fast(fmaf(hv.y, A1.y, A1.x) * gain);                        \
        yv.z = tanh_fast(fmaf(hv.z, A2.y, A2.x) * gain);                        \
        yv.w = tanh_fast(fmaf(hv.w, A3.y, A3.x) * gain);                        \
        float4 dv;                                                              \
        dv.x = fmaf(wsel, pv.x, wn * yv.x);                                     \
        dv.y = fmaf(wsel, pv.y, wn * yv.y);                                     \
        dv.z = fmaf(wsel, pv.z, wn * yv.z);                                     \
        dv.w = fmaf(wsel, pv.w, wn * yv.w);                                     \
        *(float4*)(dout + base0 + ((size_t)(s) << 10)) = dv;                    \
        if (do_an) *(float4*)(ystage + (s) * 16 * YPAD + cw * YPAD + off) = yv; \
    }

    SEG_EPI(0, p00, p01, p02, p03)
    SEG_EPI(1, p10, p11, p12, p13)
    SEG_EPI(2, p20, p21, p22, p23)
    SEG_EPI(3, p30, p31, p32, p33)
#undef SEG_EPI

    if (do_an) {
        __syncthreads();
        int K2 = counts[iblk + 1];
        if (K2 > 0) {
            const float2* cA2 = cisA + (size_t)(iblk + 1) * kmax * 64;
            const float2* cB2 = cisB + (size_t)(iblk + 1) * kmax * 16;
            int jloc = tid & 15, c = tid >> 4;
            int lane = tid & 63, wv = tid >> 6;
            const float4* yp0 = (const float4*)(ystage + c * YPAD);
            const float4* yp1 = (const float4*)(ystage + 16 * YPAD + c * YPAD);
            const float4* yp2 = (const float4*)(ystage + 32 * YPAD + c * YPAD);
            const float4* yp3 = (const float4*)(ystage + 48 * YPAD + c * YPAD);
            for (int jb = 0; jb < K2; jb += 16) {
                int j = jb + jloc;
                int js = (j < K2) ? j : (K2 - 1);
                float2 w1 = cA2[(size_t)js * 64 + 1];   // cis(k)
                float Wr = w1.x, Wi = -w1.y, nWi = w1.y;
                f2 hrA = 0.f, hiA = 0.f;                // packed (seg0, seg1)
                f2 hrB = 0.f, hiB = 0.f;                // packed (seg2, seg3)
#pragma unroll
                for (int i4 = 15; i4 >= 0; --i4) {
                    float4 ya = yp0[i4];
                    float4 yb = yp1[i4];
                    float4 yc = yp2[i4];
                    float4 yd = yp3[i4];
#define HSTEP(CC)                                                                   \
                    { f2 yy; yy.x = ya.CC; yy.y = yb.CC;                            \
                      f2 t = hiA * nWi + yy; f2 nr = hrA * Wr + t;                  \
                      hiA = hrA * Wi + hiA * Wr; hrA = nr; }                        \
                    { f2 yy; yy.x = yc.CC; yy.y = yd.CC;                            \
                      f2 t = hiB * nWi + yy; f2 nr = hrB * Wr + t;                  \
                      hiB = hrB * Wi + hiB * Wr; hrB = nr; }
                    HSTEP(w)
                    HSTEP(z)
                    HSTEP(y)
                    HSTEP(x)
#undef HSTEP
                }
                float2 bq = cB2[(size_t)js * 16 + c];   // rotate by cis(-64kc)
                f2 reA = hrA * bq.x + hiA * bq.y;
                f2 imA = hiA * bq.x - hrA * bq.y;
                f2 reB = hrB * bq.x + hiB * bq.y;
                f2 imB = hiB * bq.x - hrB * bq.y;
                // reduce over c within wave: lanes differing in bits 4,5 share jloc
                float4 prA = make_float4(reA.x, imA.x, reA.y, imA.y);
                float4 prB = make_float4(reB.x, imB.x, reB.y, imB.y);
#pragma unroll
                for (int d = 16; d <= 32; d <<= 1) {
                    prA.x += __shfl_xor(prA.x, d, 64);
                    prA.y += __shfl_xor(prA.y, d, 64);
                    prA.z += __shfl_xor(prA.z, d, 64);
                    prA.w += __shfl_xor(prA.w, d, 64);
                    prB.x += __shfl_xor(prB.x, d, 64);
                    prB.y += __shfl_xor(prB.y, d, 64);
                    prB.z += __shfl_xor(prB.z, d, 64);
                    prB.w += __shfl_xor(prB.w, d, 64);
                }
                if (lane < 16) {
                    part[wv * 16 + lane] = prA;          // pair (seg0,seg1)
                    part[64 + wv * 16 + lane] = prB;     // pair (seg2,seg3)
                }
                __syncthreads();
                if (tid < 32) {
                    int sel = tid >> 4, t = tid & 15;
                    int j2 = jb + t;
                    if (j2 < K2) {
                        const float4* pp = part + sel * 64;
                        float4 a0 = pp[t];
                        float4 a1 = pp[16 + t];
                        float4 a2 = pp[32 + t];
                        float4 a3 = pp[48 + t];
                        float4 acc;
                        acc.x = (a0.x + a1.x) + (a2.x + a3.x);
                        acc.y = (a0.y + a1.y) + (a2.y + a3.y);
                        acc.z = (a0.z + a1.z) + (a2.z + a3.z);
                        acc.w = (a0.w + a1.w) + (a2.w + a3.w);
                        H2[(size_t)(b * FRM + s0 + sel * 2) * K2 + j2] = make_float2(acc.x, acc.y);
                        H2[(size_t)(b * FRM + s0 + sel * 2 + 1) * K2 + j2] = make_float2(acc.z, acc.w);
                    }
                }
                __syncthreads();
            }
        }
    }
}

extern "C" void kernel_launch(void* const* d_in, const int* in_sizes, int n_in,
                              void* d_out, int out_size, void* d_ws, size_t ws_size,
                              hipStream_t stream)
{
    const float* x         = (const float*)d_in[0];
    const float* transfers = (const float*)d_in[1];
    const float* gains     = (const float*)d_in[2];
    const float* mixer     = (const float*)d_in[3];
    float* dout = (float*)d_out;

    uint8_t* ws = (uint8_t*)d_ws;
    int*   counts = (int*)ws;                          // 16 B
    int*   bins   = (int*)(ws + 64);                   // 4*1025*4 = 16400 B
    float* tvals  = (float*)(ws + 64 + 16400);         // 16400 B
    float* wmix   = (float*)(ws + 64 + 16400 + 16400); // 20 B
    float* hann   = (float*)(ws + 36864);              // 1024 floats
    const size_t HDR = 65536;

    // per-k bytes: two ping-pong S buffers (2*BAT*FRM*8) + cisA (NB*64*8) + cisB (NB*16*8)
    long long perk = 2LL * BAT * FRM * 8 + (long long)NB * 80 * 8;
    long long km = ((long long)ws_size - (long long)HDR) / perk;
    int kmax = (int)((km < 1) ? 1 : ((km > NC) ? NC : km));
    float2* S0 = (float2*)(ws + HDR);
    float2* S1 = S0 + (size_t)BAT * FRM * kmax;
    float2* cisA = S1 + (size_t)BAT * FRM * kmax;      // NB * kmax * 64 float2
    float2* cisB = cisA + (size_t)NB * kmax * 64;      // NB * kmax * 16 float2

    setup_kernel<<<NB, 1024, 0, stream>>>(transfers, mixer, counts, bins, tvals, wmix, hann,
                                          cisA, cisB, kmax);
    analysis_kernel<<<BAT * FRM, 256, 0, stream>>>(x, counts, cisA, cisB, S0, 0, kmax);

    float2* cur = S0;
    float2* nxt = S1;
    for (int i = 0; i < NB; ++i) {
        scan_kernel<<<BAT * 32, 256, 0, stream>>>(cur, counts, bins, tvals, i);
        fused_synth_kernel<<<BAT * (FRM / SEGS), 256, 0, stream>>>(cur, nxt, cisA, cisB, counts, bins,
                                                                   gains, wmix, hann, x, dout, i,
                                                                   (i < NB - 1) ? 1 : 0, kmax);
        float2* t = cur; cur = nxt; nxt = t;
    }
}

// Round 10
// 233.279 us; speedup vs baseline: 1.2661x; 1.0079x over previous
//
#include <hip/hip_runtime.h>
#include <math.h>
#include <stdint.h>

#define NB   4
#define NC   1025
#define WSZ  2048
#define STEP 1024
#define FRM  256
#define BAT  32
#define TT   262144
#define SEGS 4       // segments (frames) per workgroup in fused synth
#define KC   16      // bin chunk per rc-build in the synth kernel
#define YPAD 68      // floats per 64-sample ystage chunk (+4 pad: conflict-free strides)

// 1/2048 (exact): phases are integers mod 2048 -> revolutions for v_sin/v_cos
#define RREV (1.0f / 2048.0f)

typedef float f2 __attribute__((ext_vector_type(2)));

__device__ __forceinline__ float tanh_fast(float z) {
    float e = __expf(2.0f * z);
    return 1.0f - 2.0f / (e + 1.0f);   // exact tanh identity; inf/0 saturate to +/-1
}

// hardware cis: idx taken mod 2048, argument in revolutions (exact, no range reduction)
__device__ __forceinline__ void cis_rev(int idx, float* c, float* s) {
    float rev = (float)(idx & 2047) * RREV;
    *c = __builtin_amdgcn_cosf(rev);
    *s = __builtin_amdgcn_sinf(rev);
}

// ---------------- setup + tables fused: compact bins, softmax(mixer), hann, cisA/cisB ----------------
__global__ __launch_bounds__(1024) void setup_kernel(
    const float* __restrict__ transfers, const float* __restrict__ mixer,
    int* __restrict__ counts, int* __restrict__ bins, float* __restrict__ tvals,
    float* __restrict__ wmix, float* __restrict__ hann,
    float2* __restrict__ cisA, float2* __restrict__ cisB, int kmax)
{
    int i = blockIdx.x, tid = threadIdx.x;
    __shared__ int wcnt[16], woff[16];
    __shared__ int sK;
    if (i == 0) {                                   // hann[n] = 0.5 - 0.5 cos(2pi n/2048)
        float cc, ss; cis_rev(tid, &cc, &ss);
        hann[tid] = 0.5f - 0.5f * cc;
    }
    float tv = transfers[i * NC + tid];
    bool nz = (tv != 0.0f);
    unsigned long long mask = __ballot(nz);
    int lane = tid & 63, w = tid >> 6;
    int within = __popcll(mask & ((1ULL << lane) - 1ULL));
    if (lane == 0) wcnt[w] = __popcll(mask);
    __syncthreads();
    if (tid == 0) {
        int acc = 0;
        for (int q = 0; q < 16; ++q) { woff[q] = acc; acc += wcnt[q]; }
        float tvL = transfers[i * NC + 1024];       // tail bin k=1024
        if (tvL != 0.0f && acc < kmax) { bins[i * NC + acc] = 1024; tvals[i * NC + acc] = tvL; acc++; }
        int kk = (acc < kmax) ? acc : kmax;
        counts[i] = kk;
        sK = kk;
        if (i == 0) {                               // softmax of mixer[5]
            float m = mixer[0];
            for (int q = 1; q < 5; ++q) m = fmaxf(m, mixer[q]);
            float e[5], s = 0.f;
            for (int q = 0; q < 5; ++q) { e[q] = __expf(mixer[q] - m); s += e[q]; }
            for (int q = 0; q < 5; ++q) wmix[q] = e[q] / s;
        }
    }
    __syncthreads();
    if (nz) {
        int pos = woff[w] + within;
        if (pos < kmax) { bins[i * NC + pos] = tid; tvals[i * NC + pos] = tv; }
    }
    __syncthreads();                                // bins visible to table phase
    int K = sK;
    // table phase: cisA[i][j][m] = cis(2pi k_j m/2048) m<64; cisB[i][j][q] = cis(2pi k_j 64q/2048) q<16
    for (int flat = tid; flat < K * 80; flat += 1024) {
        int j = flat / 80, r = flat - j * 80;
        int k = bins[i * NC + j];
        if (r < 64) {
            float cc, ss; cis_rev(k * r, &cc, &ss);
            cisA[((size_t)i * kmax + j) * 64 + r] = make_float2(cc, ss);
        } else {
            int q = r - 64;
            float cc, ss; cis_rev(k * 64 * q, &cc, &ss);
            cisB[((size_t)i * kmax + j) * 16 + q] = make_float2(cc, ss);
        }
    }
}

// shared half-frame DFT (standalone analysis of x only): xr[16] per lane (n = lane + 64*i),
// bins j = w, w+4, ... < K; W = conj(cisB[j][1]); final rotate by conj(cisA[j][lane]).
__device__ __forceinline__ void half_dft(
    const float xr[16], int K, const float2* __restrict__ cA,
    const float2* __restrict__ cB, float2* __restrict__ Hout, int lane, int w)
{
    for (int j = w; j < K; j += 8) {
        int j2 = j + 4;
        bool two = (j2 < K);
        float2 bA = cB[(size_t)j * 16 + 1];
        float2 bB = two ? cB[(size_t)j2 * 16 + 1] : bA;
        float2 wAl = cA[(size_t)j * 64 + lane];
        float2 wBl = two ? cA[(size_t)j2 * 64 + lane] : wAl;
        f2 Wr, Wi, nWi;
        Wr.x = bA.x; Wr.y = bB.x;
        Wi.x = -bA.y; Wi.y = -bB.y;              // W = conj(cis(64k))
        nWi = -Wi;
        f2 hr = 0.f, hi = 0.f;                   // packed Horner: lane0=binA, lane1=binB
#pragma unroll
        for (int i = 15; i >= 0; --i) {
            f2 xx; xx.x = xr[i]; xx.y = xr[i];
            f2 tmp = nWi * hi + xx;              // pk_fma
            f2 nr = Wr * hr + tmp;               // pk_fma
            hi = Wi * hr + Wr * hi;
            hr = nr;
        }
        f2 wlc, wls;
        wlc.x = wAl.x; wlc.y = wBl.x;
        wls.x = wAl.y; wls.y = wBl.y;
        f2 re = hr * wlc + hi * wls;
        f2 im = hi * wlc - hr * wls;
        float reA = re.x, imA = im.x, reB = re.y, imB = im.y;
#pragma unroll
        for (int m = 32; m >= 1; m >>= 1) {
            reA += __shfl_xor(reA, m, 64);
            imA += __shfl_xor(imA, m, 64);
            reB += __shfl_xor(reB, m, 64);
            imB += __shfl_xor(imB, m, 64);
        }
        if (lane == 0) {
            Hout[j] = make_float2(reA, imA);
            if (two) Hout[j2] = make_float2(reB, imB);
        }
    }
}

// ---------------- analysis (block 0 only): sparse DFT of each 1024-sample half-frame ----------------
__global__ __launch_bounds__(256, 8) void analysis_kernel(
    const float* __restrict__ x, const int* __restrict__ counts,
    const float2* __restrict__ cisA, const float2* __restrict__ cisB,
    float2* __restrict__ H, int iblk, int kmax)
{
    int wg = blockIdx.x;
    int b = wg >> 8, h = wg & 255;
    int tid = threadIdx.x;
    int lane = tid & 63, w = tid >> 6;
    int K = counts[iblk];
    const float* xb = x + (size_t)b * TT + (size_t)h * STEP;
    float xr[16];
#pragma unroll
    for (int i = 0; i < 16; ++i) xr[i] = xb[lane + (i << 6)];
    const float2* cA = cisA + (size_t)iblk * kmax * 64;
    const float2* cB = cisB + (size_t)iblk * kmax * 16;
    float2* Hout = H + (size_t)(b * FRM + h) * K;
    half_dft(xr, K, cA, cB, Hout, lane, w);
}

// ---------------- scan: S_f = H_f + (-1)^k H_{f+1};  O_f = (S_f + O_{f-1}) * t ----------------
// Constant-coefficient first-order recurrence: in-wave shuffle scan (t^d by squaring)
// + one LDS cross-wave combine. (Exact round-3 version -- best measured total.)
__global__ __launch_bounds__(256) void scan_kernel(
    float2* __restrict__ S, const int* __restrict__ counts,
    const int* __restrict__ bins, const float* __restrict__ tvals, int iblk)
{
    int K = counts[iblk];
    int wg = blockIdx.x;
    int b = wg & (BAT - 1), j0 = wg >> 5;
    int f = threadIdx.x;
    int lane = f & 63, w = f >> 6;
    __shared__ float2 wtot[4];
    for (int j = j0; j < K; j += 32) {
        float t = tvals[iblk * NC + j];
        int k = bins[iblk * NC + j];
        float2* Sb = S + (size_t)b * FRM * K + j;
        float2 h1 = Sb[(size_t)f * K];
        float2 h2 = (f < FRM - 1) ? Sb[(size_t)(f + 1) * K] : make_float2(0.f, 0.f);
        float sgn = (k & 1) ? -t : t;
        float ax = fmaf(sgn, h2.x, h1.x * t);    // a_f = t*S_f
        float ay = fmaf(sgn, h2.y, h1.y * t);
        float td = t;
        float tp0, tp1, tp2, tp3, tp4, tp5;
#pragma unroll
        for (int s = 0; s < 6; ++s) {
            int d = 1 << s;
            if (s == 0) tp0 = td; else if (s == 1) tp1 = td; else if (s == 2) tp2 = td;
            else if (s == 3) tp3 = td; else if (s == 4) tp4 = td; else tp5 = td;
            float bx = __shfl_up(ax, d, 64);
            float by = __shfl_up(ay, d, 64);
            if (lane >= d) { ax = fmaf(td, bx, ax); ay = fmaf(td, by, ay); }
            td *= td;                            // after loop: td = t^64
        }
        if (lane == 63) wtot[w] = make_float2(ax, ay);
        __syncthreads();
        float px = 0.f, py = 0.f;
#pragma unroll
        for (int w2 = 0; w2 < 3; ++w2) {
            if (w2 < w) {
                float2 v = wtot[w2];
                px = fmaf(px, td, v.x);
                py = fmaf(py, td, v.y);
            }
        }
        int n = lane + 1;
        float fac = (n & 64) ? td : 1.0f;
        if (n & 1)  fac *= tp0;
        if (n & 2)  fac *= tp1;
        if (n & 4)  fac *= tp2;
        if (n & 8)  fac *= tp3;
        if (n & 16) fac *= tp4;
        if (n & 32) fac *= tp5;
        ax = fmaf(fac, px, ax);
        ay = fmaf(fac, py, ay);
        Sb[(size_t)f * K] = make_float2(ax, ay);
        __syncthreads();                         // wtot reused next j-iteration
    }
}

// accumulate 4 samples for one (seg, bin): acc_i += up*c_i + vp*s_i
__device__ __forceinline__ void acc4(
    f2& q0, f2& q1, f2& q2, f2& q3, float4 e, float4 a0, float4 a1)
{
    f2 up; up.x = e.x; up.y = e.y;
    f2 vp; vp.x = e.z; vp.y = e.w;
    q0 = up * a0.x + q0; q0 = vp * a0.y + q0;
    q1 = up * a0.z + q1; q1 = vp * a0.w + q1;
    q2 = up * a1.x + q2; q2 = vp * a1.y + q2;
    q3 = up * a1.z + q3; q3 = vp * a1.w + q3;
}

// ---------------- fused synthesis (SEGS=4 segments/wg) + next-block analysis ----------------
// Round-3 core + grouped epilogue loads (R9 intent; R9 FAILED only due to a typo in the
// K-loop tail: acc4(p20,p21,p23,p23,...) -- fixed to p22 here). For iblk>0 prevsrc==dout,
// so per-seg load/store interleave serialized 4 HBM round trips; grouping all pv loads
// before any store lets them pipeline under one vmcnt wait (R1's best-ever 41.56us had
// loads hoisted -- consistent).
__global__ __launch_bounds__(256, 5) void fused_synth_kernel(
    const float2* __restrict__ S, float2* __restrict__ H2,
    const float2* __restrict__ cisA, const float2* __restrict__ cisB,
    const int* __restrict__ counts, const int* __restrict__ bins,
    const float* __restrict__ gains, const float* __restrict__ wmix,
    const float* __restrict__ hann, const float* __restrict__ x,
    float* __restrict__ dout, int iblk, int do_an, int kmax)
{
    // union: rc (synth phase, 1024 f4) overlaps ystage (1088 f4); part sits above both
    __shared__ float4 smem[1216];                 // 19456 B
    float4* rc = smem;                            // [SEGS][KC][16] float4 = 16 KB
    float*  ystage = (float*)smem;                // [SEGS][16][YPAD] floats = 17408 B
    float4* part = smem + 1088;                   // [2][4][16] float4 = 2 KB

    int wg = blockIdx.x;
    int b = wg >> 6, s0 = (wg & 63) << 2;
    int tid = threadIdx.x;
    int n1 = tid << 2;
    int q = tid >> 4;            // [0,16)
    int m = (tid & 15) << 2;     // [0,64) step 4

    int K = counts[iblk];
    const int* bl = bins + iblk * NC;
    const float2* Ob = S + (size_t)b * FRM * K;
    const float2* cA0 = cisA + (size_t)iblk * kmax * 64;
    const float2* cB0 = cisB + (size_t)iblk * kmax * 16;

    f2 p00 = 0.f, p01 = 0.f, p02 = 0.f, p03 = 0.f;   // seg s0
    f2 p10 = 0.f, p11 = 0.f, p12 = 0.f, p13 = 0.f;   // seg s0+1
    f2 p20 = 0.f, p21 = 0.f, p22 = 0.f, p23 = 0.f;   // seg s0+2
    f2 p30 = 0.f, p31 = 0.f, p32 = 0.f, p33 = 0.f;   // seg s0+3

    for (int c0 = 0; c0 < K; c0 += KC) {
        int cs = (K - c0 < KC) ? (K - c0) : KC;
        {   // build rc: 4 threads per (seg,j), each does 4 q-entries
            int flat = tid >> 2;                  // 0..63 = seg*KC + j
            int seg = flat >> 4;
            int j = flat & 15;
            int jj = c0 + ((j < cs) ? j : (cs - 1));
            int q0 = (tid & 3) << 2;
            int k = bl[jj];
            float g = ((k == 0) || (k == 1024)) ? (1.0f / 2048.0f) : (2.0f / 2048.0f);
            float sg = (k & 1) ? -g : g;
            int fc = s0 + seg;
            float2 o1 = Ob[(size_t)fc * K + jj];
            float2 om = (fc > 0) ? Ob[(size_t)(fc - 1) * K + jj] : make_float2(0.f, 0.f);
            float c2r = om.x * sg, c2i = om.y * sg;
            f2 u; u.x = c2r;  u.y = o1.x * g - c2r;
            f2 v; v.x = -c2i; v.y = -(o1.y * g - c2i);
            const float2* bqp = cB0 + (size_t)jj * 16 + q0;
#pragma unroll
            for (int e = 0; e < 4; ++e) {
                float2 bq = bqp[e];
                f2 up = u * bq.x + v * bq.y;
                f2 vp = v * bq.x - u * bq.y;
                rc[(flat << 4) + q0 + e] = make_float4(up.x, up.y, vp.x, vp.y);
            }
        }
        __syncthreads();
        const float2* cAj = cA0 + ((size_t)c0 << 6) + m;
        const float4* rcq = rc + q;
        int jj = 0;
        for (; jj + 2 <= cs; jj += 2) {
            float4 a00 = *(const float4*)(cAj);
            float4 a01 = *(const float4*)(cAj + 2);
            float4 a10 = *(const float4*)(cAj + 64);
            float4 a11 = *(const float4*)(cAj + 66);
            cAj += 128;
            {   // seg 0
                float4 e0 = rcq[(0 * KC + jj) << 4];
                float4 e1 = rcq[(0 * KC + jj + 1) << 4];
                acc4(p00, p01, p02, p03, e0, a00, a01);
                acc4(p00, p01, p02, p03, e1, a10, a11);
            }
            {   // seg 1
                float4 e0 = rcq[(1 * KC + jj) << 4];
                float4 e1 = rcq[(1 * KC + jj + 1) << 4];
                acc4(p10, p11, p12, p13, e0, a00, a01);
                acc4(p10, p11, p12, p13, e1, a10, a11);
            }
            {   // seg 2
                float4 e0 = rcq[(2 * KC + jj) << 4];
                float4 e1 = rcq[(2 * KC + jj + 1) << 4];
                acc4(p20, p21, p22, p23, e0, a00, a01);
                acc4(p20, p21, p22, p23, e1, a10, a11);
            }
            {   // seg 3
                float4 e0 = rcq[(3 * KC + jj) << 4];
                float4 e1 = rcq[(3 * KC + jj + 1) << 4];
                acc4(p30, p31, p32, p33, e0, a00, a01);
                acc4(p30, p31, p32, p33, e1, a10, a11);
            }
        }
        if (jj < cs) {
            float4 a0 = *(const float4*)(cAj);
            float4 a1 = *(const float4*)(cAj + 2);
            float4 e0 = rcq[(0 * KC + jj) << 4];
            float4 e1 = rcq[(1 * KC + jj) << 4];
            float4 e2 = rcq[(2 * KC + jj) << 4];
            float4 e3 = rcq[(3 * KC + jj) << 4];
            acc4(p00, p01, p02, p03, e0, a0, a1);
            acc4(p10, p11, p12, p13, e1, a0, a1);
            acc4(p20, p21, p22, p23, e2, a0, a1);
            acc4(p30, p31, p32, p33, e3, a0, a1);
        }
        __syncthreads();
    }

    // epilogue: issue ALL prev loads first (prevsrc aliases dout for iblk>0 -- grouped
    // loads avoid 4 serial load/store round trips), then compute + store per seg.
    size_t base0 = (size_t)b * TT + ((size_t)s0 << 10) + (size_t)n1;
    const float* prevsrc = (iblk == 0) ? x : dout;
    float4 pva0 = *(const float4*)(prevsrc + base0);
    float4 pva1 = *(const float4*)(prevsrc + base0 + 1024);
    float4 pva2 = *(const float4*)(prevsrc + base0 + 2048);
    float4 pva3 = *(const float4*)(prevsrc + base0 + 3072);
    float4 hv = *(const float4*)(hann + n1);
    float gain = gains[iblk];
    float wsel = (iblk == 0) ? wmix[0] : 1.0f;
    float wn = wmix[iblk + 1];
    int cw = n1 >> 6, off = n1 & 63;

#define SEG_EPI(s, PV, A0, A1, A2, A3)                                          \
    {                                                                           \
        float4 yv;                                                              \
        yv.x = tanh_fast(fmaf(hv.x, A0.y, A0.x) * gain);                        \
        yv.y = tanh_fast(fmaf(hv.y, A1.y, A1.x) * gain);                        \
        yv.z = tanh_fast(fmaf(hv.z, A2.y, A2.x) * gain);                        \
        yv.w = tanh_fast(fmaf(hv.w, A3.y, A3.x) * gain);                        \
        float4 dv;                                                              \
        dv.x = fmaf(wsel, PV.x, wn * yv.x);                                     \
        dv.y = fmaf(wsel, PV.y, wn * yv.y);                                     \
        dv.z = fmaf(wsel, PV.z, wn * yv.z);                                     \
        dv.w = fmaf(wsel, PV.w, wn * yv.w);                                     \
        *(float4*)(dout + base0 + ((size_t)(s) << 10)) = dv;                    \
        if (do_an) *(float4*)(ystage + (s) * 16 * YPAD + cw * YPAD + off) = yv; \
    }

    SEG_EPI(0, pva0, p00, p01, p02, p03)
    SEG_EPI(1, pva1, p10, p11, p12, p13)
    SEG_EPI(2, pva2, p20, p21, p22, p23)
    SEG_EPI(3, pva3, p30, p31, p32, p33)
#undef SEG_EPI

    if (do_an) {
        __syncthreads();
        int K2 = counts[iblk + 1];
        if (K2 > 0) {
            const float2* cA2 = cisA + (size_t)(iblk + 1) * kmax * 64;
            const float2* cB2 = cisB + (size_t)(iblk + 1) * kmax * 16;
            int jloc = tid & 15, c = tid >> 4;
            int lane = tid & 63, wv = tid >> 6;
            const float4* yp0 = (const float4*)(ystage + c * YPAD);
            const float4* yp1 = (const float4*)(ystage + 16 * YPAD + c * YPAD);
            const float4* yp2 = (const float4*)(ystage + 32 * YPAD + c * YPAD);
            const float4* yp3 = (const float4*)(ystage + 48 * YPAD + c * YPAD);
            for (int jb = 0; jb < K2; jb += 16) {
                int j = jb + jloc;
                int js = (j < K2) ? j : (K2 - 1);
                float2 w1 = cA2[(size_t)js * 64 + 1];   // cis(k)
                float Wr = w1.x, Wi = -w1.y, nWi = w1.y;
                f2 hrA = 0.f, hiA = 0.f;                // packed (seg0, seg1)
                f2 hrB = 0.f, hiB = 0.f;                // packed (seg2, seg3)
#pragma unroll
                for (int i4 = 15; i4 >= 0; --i4) {
                    float4 ya = yp0[i4];
                    float4 yb = yp1[i4];
                    float4 yc = yp2[i4];
                    float4 yd = yp3[i4];
#define HSTEP(CC)                                                                   \
                    { f2 yy; yy.x = ya.CC; yy.y = yb.CC;                            \
                      f2 t = hiA * nWi + yy; f2 nr = hrA * Wr + t;                  \
                      hiA = hrA * Wi + hiA * Wr; hrA = nr; }                        \
                    { f2 yy; yy.x = yc.CC; yy.y = yd.CC;                            \
                      f2 t = hiB * nWi + yy; f2 nr = hrB * Wr + t;                  \
                      hiB = hrB * Wi + hiB * Wr; hrB = nr; }
                    HSTEP(w)
                    HSTEP(z)
                    HSTEP(y)
                    HSTEP(x)
#undef HSTEP
                }
                float2 bq = cB2[(size_t)js * 16 + c];   // rotate by cis(-64kc)
                f2 reA = hrA * bq.x + hiA * bq.y;
                f2 imA = hiA * bq.x - hrA * bq.y;
                f2 reB = hrB * bq.x + hiB * bq.y;
                f2 imB = hiB * bq.x - hrB * bq.y;
                // reduce over c within wave: lanes differing in bits 4,5 share jloc
                float4 prA = make_float4(reA.x, imA.x, reA.y, imA.y);
                float4 prB = make_float4(reB.x, imB.x, reB.y, imB.y);
#pragma unroll
                for (int d = 16; d <= 32; d <<= 1) {
                    prA.x += __shfl_xor(prA.x, d, 64);
                    prA.y += __shfl_xor(prA.y, d, 64);
                    prA.z += __shfl_xor(prA.z, d, 64);
                    prA.w += __shfl_xor(prA.w, d, 64);
                    prB.x += __shfl_xor(prB.x, d, 64);
                    prB.y += __shfl_xor(prB.y, d, 64);
                    prB.z += __shfl_xor(prB.z, d, 64);
                    prB.w += __shfl_xor(prB.w, d, 64);
                }
                if (lane < 16) {
                    part[wv * 16 + lane] = prA;          // pair (seg0,seg1)
                    part[64 + wv * 16 + lane] = prB;     // pair (seg2,seg3)
                }
                __syncthreads();
                if (tid < 32) {
                    int sel = tid >> 4, t = tid & 15;
                    int j2 = jb + t;
                    if (j2 < K2) {
                        const float4* pp = part + sel * 64;
                        float4 a0 = pp[t];
                        float4 a1 = pp[16 + t];
                        float4 a2 = pp[32 + t];
                        float4 a3 = pp[48 + t];
                        float4 acc;
                        acc.x = (a0.x + a1.x) + (a2.x + a3.x);
                        acc.y = (a0.y + a1.y) + (a2.y + a3.y);
                        acc.z = (a0.z + a1.z) + (a2.z + a3.z);
                        acc.w = (a0.w + a1.w) + (a2.w + a3.w);
                        H2[(size_t)(b * FRM + s0 + sel * 2) * K2 + j2] = make_float2(acc.x, acc.y);
                        H2[(size_t)(b * FRM + s0 + sel * 2 + 1) * K2 + j2] = make_float2(acc.z, acc.w);
                    }
                }
                __syncthreads();
            }
        }
    }
}

extern "C" void kernel_launch(void* const* d_in, const int* in_sizes, int n_in,
                              void* d_out, int out_size, void* d_ws, size_t ws_size,
                              hipStream_t stream)
{
    const float* x         = (const float*)d_in[0];
    const float* transfers = (const float*)d_in[1];
    const float* gains     = (const float*)d_in[2];
    const float* mixer     = (const float*)d_in[3];
    float* dout = (float*)d_out;

    uint8_t* ws = (uint8_t*)d_ws;
    int*   counts = (int*)ws;                          // 16 B
    int*   bins   = (int*)(ws + 64);                   // 4*1025*4 = 16400 B
    float* tvals  = (float*)(ws + 64 + 16400);         // 16400 B
    float* wmix   = (float*)(ws + 64 + 16400 + 16400); // 20 B
    float* hann   = (float*)(ws + 36864);              // 1024 floats
    const size_t HDR = 65536;

    // per-k bytes: two ping-pong S buffers (2*BAT*FRM*8) + cisA (NB*64*8) + cisB (NB*16*8)
    long long perk = 2LL * BAT * FRM * 8 + (long long)NB * 80 * 8;
    long long km = ((long long)ws_size - (long long)HDR) / perk;
    int kmax = (int)((km < 1) ? 1 : ((km > NC) ? NC : km));
    float2* S0 = (float2*)(ws + HDR);
    float2* S1 = S0 + (size_t)BAT * FRM * kmax;
    float2* cisA = S1 + (size_t)BAT * FRM * kmax;      // NB * kmax * 64 float2
    float2* cisB = cisA + (size_t)NB * kmax * 64;      // NB * kmax * 16 float2

    setup_kernel<<<NB, 1024, 0, stream>>>(transfers, mixer, counts, bins, tvals, wmix, hann,
                                          cisA, cisB, kmax);
    analysis_kernel<<<BAT * FRM, 256, 0, stream>>>(x, counts, cisA, cisB, S0, 0, kmax);

    float2* cur = S0;
    float2* nxt = S1;
    for (int i = 0; i < NB; ++i) {
        scan_kernel<<<BAT * 32, 256, 0, stream>>>(cur, counts, bins, tvals, i);
        fused_synth_kernel<<<BAT * (FRM / SEGS), 256, 0, stream>>>(cur, nxt, cisA, cisB, counts, bins,
                                                                   gains, wmix, hann, x, dout, i,
                                                                   (i < NB - 1) ? 1 : 0, kmax);
        float2* t = cur; cur = nxt; nxt = t;
    }
}